// Round 1
// baseline (205.342 us; speedup 1.0000x reference)
//
#include <hip/hip_runtime.h>
#include <stdint.h>

#define T_SEQ 2048
#define CDIM 1024
#define NHEAD 16
#define HDIM 64
#define MROWS 4096   // B*T

typedef unsigned short u16;
typedef __attribute__((ext_vector_type(8))) short bf16x8;
typedef __attribute__((ext_vector_type(4))) float f32x4;
typedef __attribute__((ext_vector_type(4))) unsigned short u16x4;

__device__ __forceinline__ u16 f2bf(float f) {
  unsigned u = __builtin_bit_cast(unsigned, f);
  u += 0x7fffu + ((u >> 16) & 1u);
  return (u16)(u >> 16);
}

__device__ __forceinline__ void gll16(const void* g, void* l) {
  __builtin_amdgcn_global_load_lds((__attribute__((address_space(1))) void*)(g),
                                   (__attribute__((address_space(3))) void*)(l),
                                   16, 0, 0);
}

__global__ void cvt_f32_bf16(const float* __restrict__ src, u16* __restrict__ dst, int n4) {
  int stride = gridDim.x * blockDim.x;
  for (int i = blockIdx.x * blockDim.x + threadIdx.x; i < n4; i += stride) {
    float4 a = ((const float4*)src)[i];
    u16x4 o = { f2bf(a.x), f2bf(a.y), f2bf(a.z), f2bf(a.w) };
    ((u16x4*)dst)[i] = o;
  }
}

// C = A @ Bw^T (+bias). A:[4096][1024] bf16 row-major, Bw:[1024][1024] bf16 row-major [n][k].
// MODE 0: fp32 out row-major [4096][1024]
// MODE 1: bf16 out head layout [B][H][T][Dh], value=(acc+bias)*scale
// MODE 2: bf16 out transposed head layout [B][H][Dh][T]
template<int MODE>
__global__ __launch_bounds__(256)
void gemm_bt(const u16* __restrict__ A, const u16* __restrict__ Bw,
             const float* __restrict__ bias, void* __restrict__ outp, float scale) {
  __shared__ u16 As[128 * 64];
  __shared__ u16 Bs[128 * 64];
  const int m0 = blockIdx.y * 128;
  const int n0 = blockIdx.x * 128;
  const int tid = threadIdx.x;
  const int w = tid >> 6, l = tid & 63;
  const int wr = w >> 1, wc = w & 1;
  const int lg = l >> 4, lr = l & 15;

  f32x4 acc[4][4] = {};

  for (int kt = 0; kt < 16; ++kt) {
    __syncthreads();
    const int k0 = kt * 64;
#pragma unroll
    for (int c = 0; c < 4; ++c) {
      int idx = c * 256 + tid;
      int row = idx >> 3, slot = idx & 7;
      int koff = k0 + ((slot ^ (row & 7)) << 3);
      gll16(A  + (size_t)(m0 + row) * CDIM + koff, As + (size_t)(c * 256 + w * 64) * 8);
      gll16(Bw + (size_t)(n0 + row) * CDIM + koff, Bs + (size_t)(c * 256 + w * 64) * 8);
    }
    __syncthreads();
#pragma unroll
    for (int kk = 0; kk < 2; ++kk) {
      bf16x8 af[4], bfr[4];
#pragma unroll
      for (int f = 0; f < 4; ++f) {
        int ra = wr * 64 + f * 16 + lr;
        af[f]  = *(const bf16x8*)((const char*)As + ra * 128 + ((lg * 16 + kk * 64) ^ ((ra & 7) << 4)));
        int rb = wc * 64 + f * 16 + lr;
        bfr[f] = *(const bf16x8*)((const char*)Bs + rb * 128 + ((lg * 16 + kk * 64) ^ ((rb & 7) << 4)));
      }
#pragma unroll
      for (int i = 0; i < 4; ++i)
#pragma unroll
        for (int j = 0; j < 4; ++j)
          acc[i][j] = __builtin_amdgcn_mfma_f32_16x16x32_bf16(af[i], bfr[j], acc[i][j], 0, 0, 0);
    }
  }

#pragma unroll
  for (int fj = 0; fj < 4; ++fj) {
    int col = n0 + wc * 64 + fj * 16 + lr;
    float bv = bias[col];
#pragma unroll
    for (int fi = 0; fi < 4; ++fi) {
#pragma unroll
      for (int i = 0; i < 4; ++i) {
        int row = m0 + wr * 64 + fi * 16 + lg * 4 + i;
        float val = acc[fi][fj][i] + bv;
        if (MODE == 0) {
          ((float*)outp)[(size_t)row * CDIM + col] = val;
        } else if (MODE == 1) {
          int b = row >> 11, t = row & 2047;
          int h = col >> 6, d = col & 63;
          ((u16*)outp)[(((size_t)(b * NHEAD + h)) * T_SEQ + t) * HDIM + d] = f2bf(val * scale);
        } else {
          int b = row >> 11, t = row & 2047;
          int h = col >> 6, d = col & 63;
          ((u16*)outp)[(((size_t)(b * NHEAD + h)) * HDIM + d) * T_SEQ + t] = f2bf(val);
        }
      }
    }
  }
}

// Flash attention. Qh/Kh: [B*H][T][Dh] bf16 (Q pre-scaled by log2e/8). Vt: [B*H][Dh][T] bf16.
// Ao: [B][T][C] bf16. Swapped QK^T: each wave computes S^T[kv=0..63][its 16 q-rows];
// lane lr&15 owns one q-row so softmax is in-lane + shfl_xor(16,32).
__global__ __launch_bounds__(256)
void attn_fused(const u16* __restrict__ Qh, const u16* __restrict__ Kh,
                const u16* __restrict__ Vt, u16* __restrict__ Ao) {
  __shared__ u16 Ks[64 * 64];
  __shared__ u16 Vs[64 * 64];
  __shared__ u16 Ps[4][16 * 64];
  const int bh = blockIdx.y;
  const int q0 = blockIdx.x * 64;
  const int tid = threadIdx.x;
  const int w = tid >> 6, l = tid & 63;
  const int lg = l >> 4, lr = l & 15;

  // Q fragment (B-operand): lane holds Q[q0 + w*16 + lr][8*lg + j (+32*kk)]
  const u16* qptr = Qh + ((size_t)bh * T_SEQ + q0 + w * 16 + lr) * HDIM + lg * 8;
  bf16x8 qf0 = *(const bf16x8*)qptr;
  bf16x8 qf1 = *(const bf16x8*)(qptr + 32);

  f32x4 acc[4] = {};           // O^T frags over d
  float m_run = -1e30f, l_run = 0.f;
  u16* pw = Ps[w];

  for (int kv = 0; kv < 32; ++kv) {
    __syncthreads();
    const int n0 = kv * 64;
#pragma unroll
    for (int c = 0; c < 2; ++c) {
      int idx = c * 256 + tid;
      int row = idx >> 3, slot = idx & 7;
      int so = (slot ^ (row & 7)) << 3;
      gll16(Kh + ((size_t)bh * T_SEQ + n0 + row) * HDIM + so,
            Ks + (size_t)(c * 256 + w * 64) * 8);
      gll16(Vt + ((size_t)bh * HDIM + row) * T_SEQ + n0 + so,
            Vs + (size_t)(c * 256 + w * 64) * 8);
    }
    __syncthreads();

    // S^T = K @ Q^T : D[n_kv][m_q]
    f32x4 s[4] = {};
#pragma unroll
    for (int kk = 0; kk < 2; ++kk) {
      bf16x8 qf = kk ? qf1 : qf0;
#pragma unroll
      for (int fn = 0; fn < 4; ++fn) {
        int r = fn * 16 + lr;
        bf16x8 kf = *(const bf16x8*)((const char*)Ks + r * 128 + ((lg * 16 + kk * 64) ^ ((r & 7) << 4)));
        s[fn] = __builtin_amdgcn_mfma_f32_16x16x32_bf16(kf, qf, s[fn], 0, 0, 0);
      }
    }

    // online softmax in log2 domain (scale folded into Q)
    float tmax = -1e30f;
#pragma unroll
    for (int fn = 0; fn < 4; ++fn)
      tmax = fmaxf(tmax, fmaxf(fmaxf(s[fn][0], s[fn][1]), fmaxf(s[fn][2], s[fn][3])));
    tmax = fmaxf(tmax, __shfl_xor(tmax, 16));
    tmax = fmaxf(tmax, __shfl_xor(tmax, 32));
    float m_new = fmaxf(m_run, tmax);
    float alpha = exp2f(m_run - m_new);
    m_run = m_new;

    float p[4][4];
    float tsum = 0.f;
#pragma unroll
    for (int fn = 0; fn < 4; ++fn)
#pragma unroll
      for (int i = 0; i < 4; ++i) {
        p[fn][i] = exp2f(s[fn][i] - m_new);
        tsum += p[fn][i];
      }
    tsum += __shfl_xor(tsum, 16);
    tsum += __shfl_xor(tsum, 32);
    l_run = l_run * alpha + tsum;

#pragma unroll
    for (int fd = 0; fd < 4; ++fd) {
      acc[fd][0] *= alpha; acc[fd][1] *= alpha;
      acc[fd][2] *= alpha; acc[fd][3] *= alpha;
    }

    // write P (bf16) to per-wave LDS: row m=lr, col n = fn*16 + lg*4 + i (swizzled)
#pragma unroll
    for (int fn = 0; fn < 4; ++fn) {
      u16x4 pk = { f2bf(p[fn][0]), f2bf(p[fn][1]), f2bf(p[fn][2]), f2bf(p[fn][3]) };
      *(u16x4*)((char*)pw + lr * 128 + ((fn * 32 + lg * 8) ^ ((lr & 7) << 4))) = pk;
    }

    // O^T[d][m] += sum_n Vt[d][n] * P^T[n][m]
#pragma unroll
    for (int kk = 0; kk < 2; ++kk) {
      bf16x8 pf = *(const bf16x8*)((const char*)pw + lr * 128 + ((lg * 16 + kk * 64) ^ ((lr & 7) << 4)));
#pragma unroll
      for (int fd = 0; fd < 4; ++fd) {
        int r = fd * 16 + lr;
        bf16x8 vf = *(const bf16x8*)((const char*)Vs + r * 128 + ((lg * 16 + kk * 64) ^ ((r & 7) << 4)));
        acc[fd] = __builtin_amdgcn_mfma_f32_16x16x32_bf16(vf, pf, acc[fd], 0, 0, 0);
      }
    }
  }

  float inv = 1.f / l_run;
  int b = bh >> 4, h = bh & 15;
  u16* orow = Ao + ((size_t)(b * T_SEQ + q0 + w * 16 + lr)) * CDIM + h * HDIM;
#pragma unroll
  for (int fd = 0; fd < 4; ++fd) {
    u16x4 ov = { f2bf(acc[fd][0] * inv), f2bf(acc[fd][1] * inv),
                 f2bf(acc[fd][2] * inv), f2bf(acc[fd][3] * inv) };
    *(u16x4*)(orow + fd * 16 + lg * 4) = ov;
  }
}

extern "C" void kernel_launch(void* const* d_in, const int* in_sizes, int n_in,
                              void* d_out, int out_size, void* d_ws, size_t ws_size,
                              hipStream_t stream) {
  const float* q  = (const float*)d_in[0];
  const float* k  = (const float*)d_in[1];
  const float* v  = (const float*)d_in[2];
  const float* Wq = (const float*)d_in[3];
  const float* bq = (const float*)d_in[4];
  const float* Wk = (const float*)d_in[5];
  const float* bk = (const float*)d_in[6];
  const float* Wv = (const float*)d_in[7];
  const float* bv = (const float*)d_in[8];
  const float* Wo = (const float*)d_in[9];
  const float* bo = (const float*)d_in[10];

  char* ws = (char*)d_ws;
  size_t off = 0;
  auto alloc = [&](size_t n) { void* p = ws + off; off += (n + 255) & ~(size_t)255; return p; };
  const size_t NX = (size_t)MROWS * CDIM;  // 4M elements
  const size_t NW = (size_t)CDIM * CDIM;   // 1M elements
  u16* qb  = (u16*)alloc(NX * 2);
  u16* kb  = (u16*)alloc(NX * 2);
  u16* vb  = (u16*)alloc(NX * 2);
  u16* Wqb = (u16*)alloc(NW * 2);
  u16* Wkb = (u16*)alloc(NW * 2);
  u16* Wvb = (u16*)alloc(NW * 2);
  u16* Wob = (u16*)alloc(NW * 2);
  u16* Qhp = (u16*)alloc(NX * 2);
  u16* Khp = (u16*)alloc(NX * 2);
  u16* Vtp = (u16*)alloc(NX * 2);
  u16* Aop = (u16*)alloc(NX * 2);

  cvt_f32_bf16<<<1024, 256, 0, stream>>>(q, qb, (int)(NX / 4));
  cvt_f32_bf16<<<1024, 256, 0, stream>>>(k, kb, (int)(NX / 4));
  cvt_f32_bf16<<<1024, 256, 0, stream>>>(v, vb, (int)(NX / 4));
  cvt_f32_bf16<<<512, 256, 0, stream>>>(Wq, Wqb, (int)(NW / 4));
  cvt_f32_bf16<<<512, 256, 0, stream>>>(Wk, Wkb, (int)(NW / 4));
  cvt_f32_bf16<<<512, 256, 0, stream>>>(Wv, Wvb, (int)(NW / 4));
  cvt_f32_bf16<<<512, 256, 0, stream>>>(Wo, Wob, (int)(NW / 4));

  dim3 gg(CDIM / 128, MROWS / 128);
  const float qscale = 0.18033688011112042f; // log2(e)/8 -> softmax in exp2 domain
  gemm_bt<1><<<gg, 256, 0, stream>>>(qb, Wqb, bq, Qhp, qscale);
  gemm_bt<1><<<gg, 256, 0, stream>>>(kb, Wkb, bk, Khp, 1.0f);
  gemm_bt<2><<<gg, 256, 0, stream>>>(vb, Wvb, bv, Vtp, 1.0f);

  attn_fused<<<dim3(T_SEQ / 64, 32), 256, 0, stream>>>(Qhp, Khp, Vtp, Aop);

  gemm_bt<0><<<gg, 256, 0, stream>>>(Aop, Wob, bo, d_out, 1.0f);

  (void)in_sizes; (void)n_in; (void)out_size; (void)ws_size;
}

// Round 2
// 171.781 us; speedup vs baseline: 1.1954x; 1.1954x over previous
//
#include <hip/hip_runtime.h>
#include <stdint.h>

#define T_SEQ 2048
#define CDIM 1024
#define NHEAD 16
#define HDIM 64
#define MROWS 4096   // B*T

typedef unsigned short u16;
typedef __attribute__((ext_vector_type(8))) short bf16x8;
typedef __attribute__((ext_vector_type(4))) float f32x4;
typedef __attribute__((ext_vector_type(4))) unsigned short u16x4;

#if __has_builtin(__builtin_amdgcn_exp2f)
#define EXP2(x) __builtin_amdgcn_exp2f(x)
#else
#define EXP2(x) exp2f(x)
#endif

__device__ __forceinline__ u16 f2bf(float f) {
  unsigned u = __builtin_bit_cast(unsigned, f);
  u += 0x7fffu + ((u >> 16) & 1u);
  return (u16)(u >> 16);
}

__device__ __forceinline__ unsigned cvt_pk_bf16(float lo, float hi) {
  unsigned r;
  asm("v_cvt_pk_bf16_f32 %0, %1, %2" : "=v"(r) : "v"(lo), "v"(hi));
  return r;
}

__device__ __forceinline__ void gll16(const void* g, void* l) {
  __builtin_amdgcn_global_load_lds((__attribute__((address_space(1))) void*)(g),
                                   (__attribute__((address_space(3))) void*)(l),
                                   16, 0, 0);
}

// One fused conversion pass for all 7 fp32->bf16 inputs.
__global__ __launch_bounds__(256)
void cvt_all(const float* __restrict__ q, const float* __restrict__ k, const float* __restrict__ v,
             const float* __restrict__ wq, const float* __restrict__ wk,
             const float* __restrict__ wv, const float* __restrict__ wo,
             u16* __restrict__ qb, u16* __restrict__ kb, u16* __restrict__ vb,
             u16* __restrict__ wqb, u16* __restrict__ wkb, u16* __restrict__ wvb, u16* __restrict__ wob) {
  int b = blockIdx.x;
  const float* src; u16* dst; int base;
  if (b < 1536) {
    int s = b >> 9;
    src = (s == 0) ? q : (s == 1) ? k : v;
    dst = (s == 0) ? qb : (s == 1) ? kb : vb;
    base = (b & 511) * 2048;
  } else {
    int s = (b - 1536) >> 7;
    src = (s == 0) ? wq : (s == 1) ? wk : (s == 2) ? wv : wo;
    dst = (s == 0) ? wqb : (s == 1) ? wkb : (s == 2) ? wvb : wob;
    base = ((b - 1536) & 127) * 2048;
  }
#pragma unroll
  for (int j = 0; j < 8; ++j) {
    int i = base + j * 256 + threadIdx.x;
    float4 a = ((const float4*)src)[i];
    u16x4 o = { f2bf(a.x), f2bf(a.y), f2bf(a.z), f2bf(a.w) };
    ((u16x4*)dst)[i] = o;
  }
}

// ---------------- GEMM: C = A @ Bw^T (+bias) ----------------
// A:[4096][1024] bf16, Bw:[1024][1024] bf16 [n][k].
// MODE 0: fp32 out row-major. MODE 1: bf16 head layout [B][H][T][Dh], (acc+bias)*scale.
// MODE 2: bf16 transposed head layout [B][H][Dh][T].

__device__ __forceinline__ void gemm_stage(const u16* Ag, const u16* Bg, u16* Ad, u16* Bd) {
#pragma unroll
  for (int c = 0; c < 4; ++c) {
    gll16(Ag + c * 32 * CDIM, Ad + c * 2048);
    gll16(Bg + c * 32 * CDIM, Bd + c * 2048);
  }
}

__device__ __forceinline__ void gemm_compute(const u16* As, const u16* Bs,
                                             f32x4 (&acc)[4][4],
                                             int wr, int wc, int lg, int lr) {
#pragma unroll
  for (int kk = 0; kk < 2; ++kk) {
    bf16x8 af[4], bfr[4];
#pragma unroll
    for (int f = 0; f < 4; ++f) {
      int ra = wr * 64 + f * 16 + lr;
      af[f]  = *(const bf16x8*)((const char*)As + ra * 128 + ((lg * 16 + kk * 64) ^ ((ra & 7) << 4)));
      int rb = wc * 64 + f * 16 + lr;
      bfr[f] = *(const bf16x8*)((const char*)Bs + rb * 128 + ((lg * 16 + kk * 64) ^ ((rb & 7) << 4)));
    }
#pragma unroll
    for (int i = 0; i < 4; ++i)
#pragma unroll
      for (int j = 0; j < 4; ++j)
        acc[i][j] = __builtin_amdgcn_mfma_f32_16x16x32_bf16(af[i], bfr[j], acc[i][j], 0, 0, 0);
  }
}

template<int MODE>
__global__ __launch_bounds__(256)
void gemm_bt(const u16* __restrict__ A, const u16* __restrict__ Bw,
             const float* __restrict__ bias, void* __restrict__ outp, float scale) {
  __shared__ u16 As[2][128 * 64];
  __shared__ u16 Bs[2][128 * 64];
  const int m0 = blockIdx.y * 128;
  const int n0 = blockIdx.x * 128;
  const int tid = threadIdx.x;
  const int w = tid >> 6, l = tid & 63;
  const int wr = w >> 1, wc = w & 1;
  const int lg = l >> 4, lr = l & 15;

  const int row0 = tid >> 3, slot0 = tid & 7;
  const int so = (slot0 ^ (row0 & 7)) << 3;
  const u16* Ag = A  + ((size_t)(m0 + row0)) * CDIM + so;
  const u16* Bg = Bw + ((size_t)(n0 + row0)) * CDIM + so;
  u16* Ad0 = As[0] + w * 512;  u16* Bd0 = Bs[0] + w * 512;
  u16* Ad1 = As[1] + w * 512;  u16* Bd1 = Bs[1] + w * 512;

  f32x4 acc[4][4] = {};

  gemm_stage(Ag, Bg, Ad0, Bd0);
  __syncthreads();
#pragma unroll 1
  for (int kt = 0; kt < 16; kt += 2) {
    gemm_stage(Ag + (kt + 1) * 64, Bg + (kt + 1) * 64, Ad1, Bd1);
    gemm_compute(As[0], Bs[0], acc, wr, wc, lg, lr);
    __syncthreads();
    if (kt + 2 < 16)
      gemm_stage(Ag + (kt + 2) * 64, Bg + (kt + 2) * 64, Ad0, Bd0);
    gemm_compute(As[1], Bs[1], acc, wr, wc, lg, lr);
    __syncthreads();
  }

#pragma unroll
  for (int fj = 0; fj < 4; ++fj) {
    int col = n0 + wc * 64 + fj * 16 + lr;
    float bv = bias[col];
#pragma unroll
    for (int fi = 0; fi < 4; ++fi) {
#pragma unroll
      for (int i = 0; i < 4; ++i) {
        int row = m0 + wr * 64 + fi * 16 + lg * 4 + i;
        float val = acc[fi][fj][i] + bv;
        if (MODE == 0) {
          ((float*)outp)[(size_t)row * CDIM + col] = val;
        } else if (MODE == 1) {
          int b = row >> 11, t = row & 2047;
          int h = col >> 6, d = col & 63;
          ((u16*)outp)[(((size_t)(b * NHEAD + h)) * T_SEQ + t) * HDIM + d] = f2bf(val * scale);
        } else {
          int b = row >> 11, t = row & 2047;
          int h = col >> 6, d = col & 63;
          ((u16*)outp)[(((size_t)(b * NHEAD + h)) * HDIM + d) * T_SEQ + t] = f2bf(val);
        }
      }
    }
  }
}

// ---------------- Flash attention ----------------
// Qh/Kh: [B*H][T][Dh] bf16 (Q pre-scaled by log2e/8 -> log2-domain logits).
// Vt: [B*H][Dh][T] bf16. Ao: [B][T][C] bf16.
// Swapped QK^T: wave computes S^T[kv][16 q-rows]; lane lr owns one q-row.

__device__ __forceinline__ void attn_stage(const u16* Kg, const u16* Vg, u16* Kd, u16* Vd) {
#pragma unroll
  for (int c = 0; c < 2; ++c) {
    gll16(Kg + c * 32 * HDIM,  Kd + c * 2048);
    gll16(Vg + c * 32 * T_SEQ, Vd + c * 2048);
  }
}

__device__ __forceinline__ void attn_process(const u16* Ks, const u16* Vs, u16* pw,
                                             bf16x8 qf0, bf16x8 qf1,
                                             f32x4 (&acc)[4], float& m_run, float& l_run,
                                             int lg, int lr) {
  // S^T = K @ Q^T
  f32x4 s[4] = {};
  __builtin_amdgcn_s_setprio(1);
#pragma unroll
  for (int kk = 0; kk < 2; ++kk) {
    bf16x8 qf = kk ? qf1 : qf0;
#pragma unroll
    for (int fn = 0; fn < 4; ++fn) {
      int r = fn * 16 + lr;
      bf16x8 kf = *(const bf16x8*)((const char*)Ks + r * 128 + ((lg * 16 + kk * 64) ^ ((r & 7) << 4)));
      s[fn] = __builtin_amdgcn_mfma_f32_16x16x32_bf16(kf, qf, s[fn], 0, 0, 0);
    }
  }
  __builtin_amdgcn_s_setprio(0);

  // online softmax (log2 domain), defer-max THR=8
  float tmax = fmaxf(fmaxf(fmaxf(s[0][0], s[0][1]), fmaxf(s[0][2], s[0][3])),
                     fmaxf(fmaxf(s[1][0], s[1][1]), fmaxf(s[1][2], s[1][3])));
  tmax = fmaxf(tmax, fmaxf(fmaxf(fmaxf(s[2][0], s[2][1]), fmaxf(s[2][2], s[2][3])),
                           fmaxf(fmaxf(s[3][0], s[3][1]), fmaxf(s[3][2], s[3][3]))));
  tmax = fmaxf(tmax, __shfl_xor(tmax, 16));
  tmax = fmaxf(tmax, __shfl_xor(tmax, 32));
  if (!__all(tmax <= m_run + 8.f)) {
    float m_new = fmaxf(m_run, tmax);
    float alpha = EXP2(m_run - m_new);
    l_run *= alpha;
#pragma unroll
    for (int fd = 0; fd < 4; ++fd) {
      acc[fd][0] *= alpha; acc[fd][1] *= alpha;
      acc[fd][2] *= alpha; acc[fd][3] *= alpha;
    }
    m_run = m_new;
  }

  float tsum = 0.f;
#pragma unroll
  for (int fn = 0; fn < 4; ++fn) {
    float p0 = EXP2(s[fn][0] - m_run);
    float p1 = EXP2(s[fn][1] - m_run);
    float p2 = EXP2(s[fn][2] - m_run);
    float p3 = EXP2(s[fn][3] - m_run);
    tsum += (p0 + p1) + (p2 + p3);
    uint2 pk;
    pk.x = cvt_pk_bf16(p0, p1);
    pk.y = cvt_pk_bf16(p2, p3);
    *(uint2*)((char*)pw + lr * 128 + ((fn * 32 + lg * 8) ^ ((lr & 7) << 4))) = pk;
  }
  tsum += __shfl_xor(tsum, 16);
  tsum += __shfl_xor(tsum, 32);
  l_run += tsum;

  // O^T[d][m] += sum_n Vt[d][n] * P^T[n][m]
#pragma unroll
  for (int kk = 0; kk < 2; ++kk) {
    bf16x8 pf = *(const bf16x8*)((const char*)pw + lr * 128 + ((lg * 16 + kk * 64) ^ ((lr & 7) << 4)));
    __builtin_amdgcn_s_setprio(1);
#pragma unroll
    for (int fd = 0; fd < 4; ++fd) {
      int r = fd * 16 + lr;
      bf16x8 vf = *(const bf16x8*)((const char*)Vs + r * 128 + ((lg * 16 + kk * 64) ^ ((r & 7) << 4)));
      acc[fd] = __builtin_amdgcn_mfma_f32_16x16x32_bf16(vf, pf, acc[fd], 0, 0, 0);
    }
    __builtin_amdgcn_s_setprio(0);
  }
}

__global__ __launch_bounds__(256)
void attn_fused(const u16* __restrict__ Qh, const u16* __restrict__ Kh,
                const u16* __restrict__ Vt, u16* __restrict__ Ao) {
  __shared__ u16 Ks[2][64 * 64];
  __shared__ u16 Vs[2][64 * 64];
  __shared__ u16 Ps[4][16 * 64];
  const int bh = blockIdx.y;
  const int q0 = blockIdx.x * 64;
  const int tid = threadIdx.x;
  const int w = tid >> 6, l = tid & 63;
  const int lg = l >> 4, lr = l & 15;

  const u16* qptr = Qh + ((size_t)bh * T_SEQ + q0 + w * 16 + lr) * HDIM + lg * 8;
  bf16x8 qf0 = *(const bf16x8*)qptr;
  bf16x8 qf1 = *(const bf16x8*)(qptr + 32);

  const int row0 = tid >> 3, slot0 = tid & 7;
  const int so = (slot0 ^ (row0 & 7)) << 3;
  const u16* Kg = Kh + ((size_t)bh * T_SEQ + row0) * HDIM + so;
  const u16* Vg = Vt + ((size_t)bh * HDIM + row0) * T_SEQ + so;
  u16* Kd0 = Ks[0] + w * 512;  u16* Vd0 = Vs[0] + w * 512;
  u16* Kd1 = Ks[1] + w * 512;  u16* Vd1 = Vs[1] + w * 512;

  f32x4 acc[4] = {};
  float m_run = -1e30f, l_run = 0.f;
  u16* pw = Ps[w];

  attn_stage(Kg, Vg, Kd0, Vd0);
  __syncthreads();
#pragma unroll 1
  for (int kv = 0; kv < 32; kv += 2) {
    attn_stage(Kg + (size_t)(kv + 1) * 64 * HDIM, Vg + (kv + 1) * 64, Kd1, Vd1);
    attn_process(Ks[0], Vs[0], pw, qf0, qf1, acc, m_run, l_run, lg, lr);
    __syncthreads();
    if (kv + 2 < 32)
      attn_stage(Kg + (size_t)(kv + 2) * 64 * HDIM, Vg + (kv + 2) * 64, Kd0, Vd0);
    attn_process(Ks[1], Vs[1], pw, qf0, qf1, acc, m_run, l_run, lg, lr);
    __syncthreads();
  }

  float inv = 1.f / l_run;
  int b = bh >> 4, h = bh & 15;
  u16* orow = Ao + ((size_t)(b * T_SEQ + q0 + w * 16 + lr)) * CDIM + h * HDIM;
#pragma unroll
  for (int fd = 0; fd < 4; ++fd) {
    uint2 ov;
    ov.x = cvt_pk_bf16(acc[fd][0] * inv, acc[fd][1] * inv);
    ov.y = cvt_pk_bf16(acc[fd][2] * inv, acc[fd][3] * inv);
    *(uint2*)(orow + fd * 16 + lg * 4) = ov;
  }
}

extern "C" void kernel_launch(void* const* d_in, const int* in_sizes, int n_in,
                              void* d_out, int out_size, void* d_ws, size_t ws_size,
                              hipStream_t stream) {
  const float* q  = (const float*)d_in[0];
  const float* k  = (const float*)d_in[1];
  const float* v  = (const float*)d_in[2];
  const float* Wq = (const float*)d_in[3];
  const float* bq = (const float*)d_in[4];
  const float* Wk = (const float*)d_in[5];
  const float* bk = (const float*)d_in[6];
  const float* Wv = (const float*)d_in[7];
  const float* bv = (const float*)d_in[8];
  const float* Wo = (const float*)d_in[9];
  const float* bo = (const float*)d_in[10];

  char* ws = (char*)d_ws;
  size_t off = 0;
  auto alloc = [&](size_t n) { void* p = ws + off; off += (n + 255) & ~(size_t)255; return p; };
  const size_t NX = (size_t)MROWS * CDIM;  // 4M elements
  const size_t NW = (size_t)CDIM * CDIM;   // 1M elements
  u16* qb  = (u16*)alloc(NX * 2);
  u16* kb  = (u16*)alloc(NX * 2);
  u16* vb  = (u16*)alloc(NX * 2);
  u16* Wqb = (u16*)alloc(NW * 2);
  u16* Wkb = (u16*)alloc(NW * 2);
  u16* Wvb = (u16*)alloc(NW * 2);
  u16* Wob = (u16*)alloc(NW * 2);
  u16* Qhp = (u16*)alloc(NX * 2);
  u16* Khp = (u16*)alloc(NX * 2);
  u16* Vtp = (u16*)alloc(NX * 2);
  u16* Aop = (u16*)alloc(NX * 2);

  cvt_all<<<2048, 256, 0, stream>>>(q, k, v, Wq, Wk, Wv, Wo,
                                    qb, kb, vb, Wqb, Wkb, Wvb, Wob);

  dim3 gg(CDIM / 128, MROWS / 128);
  const float qscale = 0.18033688011112042f; // log2(e)/8 -> softmax in exp2 domain
  gemm_bt<1><<<gg, 256, 0, stream>>>(qb, Wqb, bq, Qhp, qscale);
  gemm_bt<1><<<gg, 256, 0, stream>>>(kb, Wkb, bk, Khp, 1.0f);
  gemm_bt<2><<<gg, 256, 0, stream>>>(vb, Wvb, bv, Vtp, 1.0f);

  attn_fused<<<dim3(T_SEQ / 64, 32), 256, 0, stream>>>(Qhp, Khp, Vtp, Aop);

  gemm_bt<0><<<gg, 256, 0, stream>>>(Aop, Wob, bo, d_out, 1.0f);

  (void)in_sizes; (void)n_in; (void)out_size; (void)ws_size;
}

// Round 4
// 155.764 us; speedup vs baseline: 1.3183x; 1.1028x over previous
//
#include <hip/hip_runtime.h>
#include <stdint.h>

#define T_SEQ 2048
#define CDIM 1024
#define NHEAD 16
#define HDIM 64
#define MROWS 4096   // B*T

typedef unsigned short u16;
typedef __attribute__((ext_vector_type(8))) short bf16x8;
typedef __attribute__((ext_vector_type(4))) float f32x4;
typedef __attribute__((ext_vector_type(4))) unsigned short u16x4;

#if __has_builtin(__builtin_amdgcn_exp2f)
#define EXP2(x) __builtin_amdgcn_exp2f(x)
#else
#define EXP2(x) exp2f(x)
#endif

__device__ __forceinline__ u16 f2bf(float f) {
  unsigned u = __builtin_bit_cast(unsigned, f);
  u += 0x7fffu + ((u >> 16) & 1u);
  return (u16)(u >> 16);
}

__device__ __forceinline__ unsigned cvt_pk_bf16(float lo, float hi) {
  unsigned r;
  asm("v_cvt_pk_bf16_f32 %0, %1, %2" : "=v"(r) : "v"(lo), "v"(hi));
  return r;
}

__device__ __forceinline__ void gll16(const void* g, void* l) {
  __builtin_amdgcn_global_load_lds((__attribute__((address_space(1))) void*)(g),
                                   (__attribute__((address_space(3))) void*)(l),
                                   16, 0, 0);
}

// One fused conversion pass for all 7 fp32->bf16 inputs.
__global__ __launch_bounds__(256)
void cvt_all(const float* __restrict__ q, const float* __restrict__ k, const float* __restrict__ v,
             const float* __restrict__ wq, const float* __restrict__ wk,
             const float* __restrict__ wv, const float* __restrict__ wo,
             u16* __restrict__ qb, u16* __restrict__ kb, u16* __restrict__ vb,
             u16* __restrict__ wqb, u16* __restrict__ wkb, u16* __restrict__ wvb, u16* __restrict__ wob) {
  int b = blockIdx.x;
  const float* src; u16* dst; int base;
  if (b < 1536) {
    int s = b >> 9;
    src = (s == 0) ? q : (s == 1) ? k : v;
    dst = (s == 0) ? qb : (s == 1) ? kb : vb;
    base = (b & 511) * 2048;
  } else {
    int s = (b - 1536) >> 7;
    src = (s == 0) ? wq : (s == 1) ? wk : (s == 2) ? wv : wo;
    dst = (s == 0) ? wqb : (s == 1) ? wkb : (s == 2) ? wvb : wob;
    base = ((b - 1536) & 127) * 2048;
  }
#pragma unroll
  for (int j = 0; j < 8; ++j) {
    int i = base + j * 256 + threadIdx.x;
    float4 a = ((const float4*)src)[i];
    u16x4 o = { f2bf(a.x), f2bf(a.y), f2bf(a.z), f2bf(a.w) };
    ((u16x4*)dst)[i] = o;
  }
}

// ---------------- GEMM core pieces ----------------

__device__ __forceinline__ void gemm_stage(const u16* Ag, const u16* Bg, u16* Ad, u16* Bd) {
#pragma unroll
  for (int c = 0; c < 4; ++c) {
    gll16(Ag + c * 32 * CDIM, Ad + c * 2048);
    gll16(Bg + c * 32 * CDIM, Bd + c * 2048);
  }
}

__device__ __forceinline__ void gemm_compute(const u16* As, const u16* Bs,
                                             f32x4 (&acc)[4][4],
                                             int wr, int wc, int lg, int lr) {
#pragma unroll
  for (int kk = 0; kk < 2; ++kk) {
    bf16x8 af[4], bfr[4];
#pragma unroll
    for (int f = 0; f < 4; ++f) {
      int ra = wr * 64 + f * 16 + lr;
      af[f]  = *(const bf16x8*)((const char*)As + ra * 128 + ((lg * 16 + kk * 64) ^ ((ra & 7) << 4)));
      int rb = wc * 64 + f * 16 + lr;
      bfr[f] = *(const bf16x8*)((const char*)Bs + rb * 128 + ((lg * 16 + kk * 64) ^ ((rb & 7) << 4)));
    }
#pragma unroll
    for (int i = 0; i < 4; ++i)
#pragma unroll
      for (int j = 0; j < 4; ++j)
        acc[i][j] = __builtin_amdgcn_mfma_f32_16x16x32_bf16(af[i], bfr[j], acc[i][j], 0, 0, 0);
  }
}

// Fused Q/K/V projection GEMMs: z = blockIdx.z selects the projection.
// z=0: Q -> head layout [B][H][T][Dh], scaled by qscale (log2-domain fold)
// z=1: K -> head layout
// z=2: V -> transposed head layout [B][H][Dh][T]
__global__ __launch_bounds__(256)
void gemm_qkv(const u16* __restrict__ A0, const u16* __restrict__ A1, const u16* __restrict__ A2,
              const u16* __restrict__ W0, const u16* __restrict__ W1, const u16* __restrict__ W2,
              const float* __restrict__ b0, const float* __restrict__ b1, const float* __restrict__ b2,
              u16* __restrict__ o0, u16* __restrict__ o1, u16* __restrict__ o2,
              float qscale) {
  __shared__ u16 As[2][128 * 64];
  __shared__ u16 Bs[2][128 * 64];
  const int z = blockIdx.z;
  const u16* A   = (z == 0) ? A0 : (z == 1) ? A1 : A2;
  const u16* Bw  = (z == 0) ? W0 : (z == 1) ? W1 : W2;
  const float* bias = (z == 0) ? b0 : (z == 1) ? b1 : b2;
  u16* outp = (z == 0) ? o0 : (z == 1) ? o1 : o2;
  const float scale = (z == 0) ? qscale : 1.0f;

  const int m0 = blockIdx.y * 128;
  const int n0 = blockIdx.x * 128;
  const int tid = threadIdx.x;
  const int w = tid >> 6, l = tid & 63;
  const int wr = w >> 1, wc = w & 1;
  const int lg = l >> 4, lr = l & 15;

  const int row0 = tid >> 3, slot0 = tid & 7;
  const int so = (slot0 ^ (row0 & 7)) << 3;
  const u16* Ag = A  + ((size_t)(m0 + row0)) * CDIM + so;
  const u16* Bg = Bw + ((size_t)(n0 + row0)) * CDIM + so;
  u16* Ad0 = As[0] + w * 512;  u16* Bd0 = Bs[0] + w * 512;
  u16* Ad1 = As[1] + w * 512;  u16* Bd1 = Bs[1] + w * 512;

  f32x4 acc[4][4] = {};

  gemm_stage(Ag, Bg, Ad0, Bd0);
  __syncthreads();
#pragma unroll 1
  for (int kt = 0; kt < 16; kt += 2) {
    gemm_stage(Ag + (kt + 1) * 64, Bg + (kt + 1) * 64, Ad1, Bd1);
    gemm_compute(As[0], Bs[0], acc, wr, wc, lg, lr);
    __syncthreads();
    if (kt + 2 < 16)
      gemm_stage(Ag + (kt + 2) * 64, Bg + (kt + 2) * 64, Ad0, Bd0);
    gemm_compute(As[1], Bs[1], acc, wr, wc, lg, lr);
    __syncthreads();
  }

#pragma unroll
  for (int fj = 0; fj < 4; ++fj) {
    int col = n0 + wc * 64 + fj * 16 + lr;
    float bv = bias[col];
    int h = col >> 6, d = col & 63;
#pragma unroll
    for (int fi = 0; fi < 4; ++fi) {
#pragma unroll
      for (int i = 0; i < 4; ++i) {
        int row = m0 + wr * 64 + fi * 16 + lg * 4 + i;
        float val = (acc[fi][fj][i] + bv) * scale;
        int b = row >> 11, t = row & 2047;
        if (z < 2)
          outp[(((size_t)(b * NHEAD + h)) * T_SEQ + t) * HDIM + d] = f2bf(val);
        else
          outp[(((size_t)(b * NHEAD + h)) * HDIM + d) * T_SEQ + t] = f2bf(val);
      }
    }
  }
}

// O-projection: C = A @ Wo^T + bo, fp32 out row-major.
__global__ __launch_bounds__(256)
void gemm_bt0(const u16* __restrict__ A, const u16* __restrict__ Bw,
              const float* __restrict__ bias, float* __restrict__ outp) {
  __shared__ u16 As[2][128 * 64];
  __shared__ u16 Bs[2][128 * 64];
  const int m0 = blockIdx.y * 128;
  const int n0 = blockIdx.x * 128;
  const int tid = threadIdx.x;
  const int w = tid >> 6, l = tid & 63;
  const int wr = w >> 1, wc = w & 1;
  const int lg = l >> 4, lr = l & 15;

  const int row0 = tid >> 3, slot0 = tid & 7;
  const int so = (slot0 ^ (row0 & 7)) << 3;
  const u16* Ag = A  + ((size_t)(m0 + row0)) * CDIM + so;
  const u16* Bg = Bw + ((size_t)(n0 + row0)) * CDIM + so;
  u16* Ad0 = As[0] + w * 512;  u16* Bd0 = Bs[0] + w * 512;
  u16* Ad1 = As[1] + w * 512;  u16* Bd1 = Bs[1] + w * 512;

  f32x4 acc[4][4] = {};

  gemm_stage(Ag, Bg, Ad0, Bd0);
  __syncthreads();
#pragma unroll 1
  for (int kt = 0; kt < 16; kt += 2) {
    gemm_stage(Ag + (kt + 1) * 64, Bg + (kt + 1) * 64, Ad1, Bd1);
    gemm_compute(As[0], Bs[0], acc, wr, wc, lg, lr);
    __syncthreads();
    if (kt + 2 < 16)
      gemm_stage(Ag + (kt + 2) * 64, Bg + (kt + 2) * 64, Ad0, Bd0);
    gemm_compute(As[1], Bs[1], acc, wr, wc, lg, lr);
    __syncthreads();
  }

#pragma unroll
  for (int fj = 0; fj < 4; ++fj) {
    int col = n0 + wc * 64 + fj * 16 + lr;
    float bv = bias[col];
#pragma unroll
    for (int fi = 0; fi < 4; ++fi) {
#pragma unroll
      for (int i = 0; i < 4; ++i) {
        int row = m0 + wr * 64 + fi * 16 + lg * 4 + i;
        outp[(size_t)row * CDIM + col] = acc[fi][fj][i] + bv;
      }
    }
  }
}

// ---------------- Flash attention (defer-max online softmax, proven path) ----
// Qh/Kh: [B*H][T][Dh] bf16 (Q pre-scaled by log2e/8 -> log2-domain logits).
// Vt: [B*H][Dh][T] bf16. Ao: [B][T][C] bf16.
// Swapped QK^T: wave computes S^T[kv][16 q-rows]; lane lr owns one q-row.
// Row-sum kept as 4 lane-local partials (lsum), alpha-corrected on rescale
// events, reduced once at the end (saves 2 shuffles/tile vs round 2).

__device__ __forceinline__ void attn_stage(const u16* Kg, const u16* Vg, u16* Kd, u16* Vd) {
#pragma unroll
  for (int c = 0; c < 2; ++c) {
    gll16(Kg + c * 32 * HDIM,  Kd + c * 2048);
    gll16(Vg + c * 32 * T_SEQ, Vd + c * 2048);
  }
}

__device__ __forceinline__ void attn_process(const u16* Ks, const u16* Vs, u16* pw,
                                             bf16x8 qf0, bf16x8 qf1,
                                             f32x4 (&acc)[4], f32x4& lsum, float& m_run,
                                             int lg, int lr) {
  // S^T = K @ Q^T
  f32x4 s[4] = {};
  __builtin_amdgcn_s_setprio(1);
#pragma unroll
  for (int kk = 0; kk < 2; ++kk) {
    bf16x8 qf = kk ? qf1 : qf0;
#pragma unroll
    for (int fn = 0; fn < 4; ++fn) {
      int r = fn * 16 + lr;
      bf16x8 kf = *(const bf16x8*)((const char*)Ks + r * 128 + ((lg * 16 + kk * 64) ^ ((r & 7) << 4)));
      s[fn] = __builtin_amdgcn_mfma_f32_16x16x32_bf16(kf, qf, s[fn], 0, 0, 0);
    }
  }
  __builtin_amdgcn_s_setprio(0);

  // tile max for this lane's q-row (max3-friendly tree), then cross-group max
  float a0 = fmaxf(fmaxf(s[0][0], s[0][1]), s[0][2]);
  float a1 = fmaxf(fmaxf(s[0][3], s[1][0]), s[1][1]);
  float a2 = fmaxf(fmaxf(s[1][2], s[1][3]), s[2][0]);
  float a3 = fmaxf(fmaxf(s[2][1], s[2][2]), s[2][3]);
  float a4 = fmaxf(fmaxf(s[3][0], s[3][1]), s[3][2]);
  float tmax = fmaxf(fmaxf(fmaxf(a0, a1), fmaxf(a2, a3)), fmaxf(a4, s[3][3]));
  tmax = fmaxf(tmax, __shfl_xor(tmax, 16));
  tmax = fmaxf(tmax, __shfl_xor(tmax, 32));

  // defer-max: only rescale when tile max exceeds running max by > 8 (log2)
  if (!__all(tmax <= m_run + 8.f)) {
    float m_new = fmaxf(m_run, tmax);
    float alpha = EXP2(m_run - m_new);
    lsum[0] *= alpha; lsum[1] *= alpha; lsum[2] *= alpha; lsum[3] *= alpha;
#pragma unroll
    for (int fd = 0; fd < 4; ++fd) {
      acc[fd][0] *= alpha; acc[fd][1] *= alpha;
      acc[fd][2] *= alpha; acc[fd][3] *= alpha;
    }
    m_run = m_new;
  }

  // p = 2^(s - m_run); accumulate lane-local row-sum partials; pack to LDS
#pragma unroll
  for (int fn = 0; fn < 4; ++fn) {
    float p0 = EXP2(s[fn][0] - m_run);
    float p1 = EXP2(s[fn][1] - m_run);
    float p2 = EXP2(s[fn][2] - m_run);
    float p3 = EXP2(s[fn][3] - m_run);
    lsum[fn] += (p0 + p1) + (p2 + p3);
    uint2 pk;
    pk.x = cvt_pk_bf16(p0, p1);
    pk.y = cvt_pk_bf16(p2, p3);
    *(uint2*)((char*)pw + lr * 128 + ((fn * 32 + lg * 8) ^ ((lr & 7) << 4))) = pk;
  }

  // O^T[d][m] += sum_n Vt[d][n] * P^T[n][m]
#pragma unroll
  for (int kk = 0; kk < 2; ++kk) {
    bf16x8 pf = *(const bf16x8*)((const char*)pw + lr * 128 + ((lg * 16 + kk * 64) ^ ((lr & 7) << 4)));
    __builtin_amdgcn_s_setprio(1);
#pragma unroll
    for (int fd = 0; fd < 4; ++fd) {
      int r = fd * 16 + lr;
      bf16x8 vf = *(const bf16x8*)((const char*)Vs + r * 128 + ((lg * 16 + kk * 64) ^ ((r & 7) << 4)));
      acc[fd] = __builtin_amdgcn_mfma_f32_16x16x32_bf16(vf, pf, acc[fd], 0, 0, 0);
    }
    __builtin_amdgcn_s_setprio(0);
  }
}

__global__ __launch_bounds__(256)
void attn_fused(const u16* __restrict__ Qh, const u16* __restrict__ Kh,
                const u16* __restrict__ Vt, u16* __restrict__ Ao) {
  __shared__ u16 Ks[2][64 * 64];
  __shared__ u16 Vs[2][64 * 64];
  __shared__ u16 Ps[4][16 * 64];
  const int bh = blockIdx.y;
  const int q0 = blockIdx.x * 64;
  const int tid = threadIdx.x;
  const int w = tid >> 6, l = tid & 63;
  const int lg = l >> 4, lr = l & 15;

  const u16* qptr = Qh + ((size_t)bh * T_SEQ + q0 + w * 16 + lr) * HDIM + lg * 8;
  bf16x8 qf0 = *(const bf16x8*)qptr;
  bf16x8 qf1 = *(const bf16x8*)(qptr + 32);

  const int row0 = tid >> 3, slot0 = tid & 7;
  const int so = (slot0 ^ (row0 & 7)) << 3;
  const u16* Kg = Kh + ((size_t)bh * T_SEQ + row0) * HDIM + so;
  const u16* Vg = Vt + ((size_t)bh * HDIM + row0) * T_SEQ + so;
  u16* Kd0 = Ks[0] + w * 512;  u16* Vd0 = Vs[0] + w * 512;
  u16* Kd1 = Ks[1] + w * 512;  u16* Vd1 = Vs[1] + w * 512;

  f32x4 acc[4] = {};
  f32x4 lsum = {};
  float m_run = -1e30f;
  u16* pw = Ps[w];

  attn_stage(Kg, Vg, Kd0, Vd0);
  __syncthreads();
#pragma unroll 1
  for (int kv = 0; kv < 32; kv += 2) {
    attn_stage(Kg + (size_t)(kv + 1) * 64 * HDIM, Vg + (kv + 1) * 64, Kd1, Vd1);
    attn_process(Ks[0], Vs[0], pw, qf0, qf1, acc, lsum, m_run, lg, lr);
    __syncthreads();
    if (kv + 2 < 32)
      attn_stage(Kg + (size_t)(kv + 2) * 64 * HDIM, Vg + (kv + 2) * 64, Kd0, Vd0);
    attn_process(Ks[1], Vs[1], pw, qf0, qf1, acc, lsum, m_run, lg, lr);
    __syncthreads();
  }

  float lr_sum = (lsum[0] + lsum[1]) + (lsum[2] + lsum[3]);
  lr_sum += __shfl_xor(lr_sum, 16);
  lr_sum += __shfl_xor(lr_sum, 32);
  float inv = 1.f / lr_sum;

  int b = bh >> 4, h = bh & 15;
  u16* orow = Ao + ((size_t)(b * T_SEQ + q0 + w * 16 + lr)) * CDIM + h * HDIM;
#pragma unroll
  for (int fd = 0; fd < 4; ++fd) {
    uint2 ov;
    ov.x = cvt_pk_bf16(acc[fd][0] * inv, acc[fd][1] * inv);
    ov.y = cvt_pk_bf16(acc[fd][2] * inv, acc[fd][3] * inv);
    *(uint2*)(orow + fd * 16 + lg * 4) = ov;
  }
}

extern "C" void kernel_launch(void* const* d_in, const int* in_sizes, int n_in,
                              void* d_out, int out_size, void* d_ws, size_t ws_size,
                              hipStream_t stream) {
  const float* q  = (const float*)d_in[0];
  const float* k  = (const float*)d_in[1];
  const float* v  = (const float*)d_in[2];
  const float* Wq = (const float*)d_in[3];
  const float* bq = (const float*)d_in[4];
  const float* Wk = (const float*)d_in[5];
  const float* bk = (const float*)d_in[6];
  const float* Wv = (const float*)d_in[7];
  const float* bv = (const float*)d_in[8];
  const float* Wo = (const float*)d_in[9];
  const float* bo = (const float*)d_in[10];

  char* ws = (char*)d_ws;
  size_t off = 0;
  auto alloc = [&](size_t n) { void* p = ws + off; off += (n + 255) & ~(size_t)255; return p; };
  const size_t NX = (size_t)MROWS * CDIM;  // 4M elements
  const size_t NW = (size_t)CDIM * CDIM;   // 1M elements
  u16* qb  = (u16*)alloc(NX * 2);
  u16* kb  = (u16*)alloc(NX * 2);
  u16* vb  = (u16*)alloc(NX * 2);
  u16* Wqb = (u16*)alloc(NW * 2);
  u16* Wkb = (u16*)alloc(NW * 2);
  u16* Wvb = (u16*)alloc(NW * 2);
  u16* Wob = (u16*)alloc(NW * 2);
  u16* Qhp = (u16*)alloc(NX * 2);
  u16* Khp = (u16*)alloc(NX * 2);
  u16* Vtp = (u16*)alloc(NX * 2);
  u16* Aop = (u16*)alloc(NX * 2);

  cvt_all<<<2048, 256, 0, stream>>>(q, k, v, Wq, Wk, Wv, Wo,
                                    qb, kb, vb, Wqb, Wkb, Wvb, Wob);

  const float qscale = 0.18033688011112042f; // log2(e)/8 -> softmax in exp2 domain
  gemm_qkv<<<dim3(CDIM / 128, MROWS / 128, 3), 256, 0, stream>>>(
      qb, kb, vb, Wqb, Wkb, Wvb, bq, bk, bv, Qhp, Khp, Vtp, qscale);

  attn_fused<<<dim3(T_SEQ / 64, 32), 256, 0, stream>>>(Qhp, Khp, Vtp, Aop);

  gemm_bt0<<<dim3(CDIM / 128, MROWS / 128), 256, 0, stream>>>(Aop, Wob, bo, (float*)d_out);

  (void)in_sizes; (void)n_in; (void)out_size; (void)ws_size;
}

// Round 5
// 140.672 us; speedup vs baseline: 1.4597x; 1.1073x over previous
//
#include <hip/hip_runtime.h>
#include <stdint.h>

#define T_SEQ 2048
#define CDIM 1024
#define NHEAD 16
#define HDIM 64
#define MROWS 4096   // B*T

typedef unsigned short u16;
typedef __attribute__((ext_vector_type(8))) short bf16x8;
typedef __attribute__((ext_vector_type(4))) float f32x4;
typedef __attribute__((ext_vector_type(4))) unsigned short u16x4;

#if __has_builtin(__builtin_amdgcn_exp2f)
#define EXP2(x) __builtin_amdgcn_exp2f(x)
#else
#define EXP2(x) exp2f(x)
#endif

__device__ __forceinline__ u16 f2bf(float f) {
  unsigned u = __builtin_bit_cast(unsigned, f);
  u += 0x7fffu + ((u >> 16) & 1u);
  return (u16)(u >> 16);
}

__device__ __forceinline__ unsigned cvt_pk_bf16(float lo, float hi) {
  unsigned r;
  asm("v_cvt_pk_bf16_f32 %0, %1, %2" : "=v"(r) : "v"(lo), "v"(hi));
  return r;
}

__device__ __forceinline__ void gll16(const void* g, void* l) {
  __builtin_amdgcn_global_load_lds((__attribute__((address_space(1))) void*)(g),
                                   (__attribute__((address_space(3))) void*)(l),
                                   16, 0, 0);
}

// Raw workgroup barrier WITHOUT the vmcnt(0) drain __syncthreads() implies.
// Compiler-level memory fences stop IR/scheduler motion of LDS ops across it.
__device__ __forceinline__ void wg_barrier() {
  asm volatile("" ::: "memory");
  __builtin_amdgcn_s_barrier();
  asm volatile("" ::: "memory");
}

// Wait until <= N vector-memory ops outstanding (counted prefetch keep-alive).
// imm16 = vmcnt[3:0] | expcnt(7)<<4 | lgkmcnt(15)<<8  (N < 16)
#define WAIT_VM(N) do { __builtin_amdgcn_s_waitcnt(0xF00 | 0x70 | (N)); \
                        asm volatile("" ::: "memory"); } while (0)

// One fused conversion pass for all 7 fp32->bf16 inputs.
__global__ __launch_bounds__(256)
void cvt_all(const float* __restrict__ q, const float* __restrict__ k, const float* __restrict__ v,
             const float* __restrict__ wq, const float* __restrict__ wk,
             const float* __restrict__ wv, const float* __restrict__ wo,
             u16* __restrict__ qb, u16* __restrict__ kb, u16* __restrict__ vb,
             u16* __restrict__ wqb, u16* __restrict__ wkb, u16* __restrict__ wvb, u16* __restrict__ wob) {
  int b = blockIdx.x;
  const float* src; u16* dst; int base;
  if (b < 1536) {
    int s = b >> 9;
    src = (s == 0) ? q : (s == 1) ? k : v;
    dst = (s == 0) ? qb : (s == 1) ? kb : vb;
    base = (b & 511) * 2048;
  } else {
    int s = (b - 1536) >> 7;
    src = (s == 0) ? wq : (s == 1) ? wk : (s == 2) ? wv : wo;
    dst = (s == 0) ? wqb : (s == 1) ? wkb : (s == 2) ? wvb : wob;
    base = ((b - 1536) & 127) * 2048;
  }
#pragma unroll
  for (int j = 0; j < 8; ++j) {
    int i = base + j * 256 + threadIdx.x;
    float4 a = ((const float4*)src)[i];
    u16x4 o = { f2bf(a.x), f2bf(a.y), f2bf(a.z), f2bf(a.w) };
    ((u16x4*)dst)[i] = o;
  }
}

// ---------------- GEMM core pieces ----------------

__device__ __forceinline__ void gemm_stage(const u16* Ag, const u16* Bg, u16* Ad, u16* Bd) {
#pragma unroll
  for (int c = 0; c < 4; ++c) {          // 8 vm-ops total
    gll16(Ag + c * 32 * CDIM, Ad + c * 2048);
    gll16(Bg + c * 32 * CDIM, Bd + c * 2048);
  }
}

__device__ __forceinline__ void gemm_compute(const u16* As, const u16* Bs,
                                             f32x4 (&acc)[4][4],
                                             int wr, int wc, int lg, int lr) {
#pragma unroll
  for (int kk = 0; kk < 2; ++kk) {
    bf16x8 af[4], bfr[4];
#pragma unroll
    for (int f = 0; f < 4; ++f) {
      int ra = wr * 64 + f * 16 + lr;
      af[f]  = *(const bf16x8*)((const char*)As + ra * 128 + ((lg * 16 + kk * 64) ^ ((ra & 7) << 4)));
      int rb = wc * 64 + f * 16 + lr;
      bfr[f] = *(const bf16x8*)((const char*)Bs + rb * 128 + ((lg * 16 + kk * 64) ^ ((rb & 7) << 4)));
    }
#pragma unroll
    for (int i = 0; i < 4; ++i)
#pragma unroll
      for (int j = 0; j < 4; ++j)
        acc[i][j] = __builtin_amdgcn_mfma_f32_16x16x32_bf16(af[i], bfr[j], acc[i][j], 0, 0, 0);
  }
}

// Counted-vmcnt double-buffered K-loop, shared by both GEMM kernels.
// Per iter kt: [barA] nobody still reads buf[(kt+1)&1] (they read it at kt-1)
//              stage(kt+1) -> buf[(kt+1)&1]
//              WAIT_VM(8): my tile-kt loads landed (kt+1's 8 stay in flight)
//              [barB] everyone's tile-kt loads landed -> compute buf[kt&1]
#define GEMM_KLOOP(As, Bs, Ad0, Bd0, Ad1, Bd1)                                 \
  gemm_stage(Ag, Bg, Ad0, Bd0);                                                \
  _Pragma("unroll 1")                                                          \
  for (int kt = 0; kt < 16; ++kt) {                                            \
    wg_barrier();                                                              \
    int nt = (kt + 1 < 16) ? kt + 1 : 15;                                      \
    if (kt & 1) gemm_stage(Ag + nt * 64, Bg + nt * 64, Ad0, Bd0);              \
    else        gemm_stage(Ag + nt * 64, Bg + nt * 64, Ad1, Bd1);              \
    WAIT_VM(8);                                                                \
    wg_barrier();                                                              \
    gemm_compute((kt & 1) ? As[1] : As[0], (kt & 1) ? Bs[1] : Bs[0],           \
                 acc, wr, wc, lg, lr);                                         \
  }

// Fused Q/K/V projection GEMMs: z = blockIdx.z selects the projection.
__global__ __launch_bounds__(256)
void gemm_qkv(const u16* __restrict__ A0, const u16* __restrict__ A1, const u16* __restrict__ A2,
              const u16* __restrict__ W0, const u16* __restrict__ W1, const u16* __restrict__ W2,
              const float* __restrict__ b0, const float* __restrict__ b1, const float* __restrict__ b2,
              u16* __restrict__ o0, u16* __restrict__ o1, u16* __restrict__ o2,
              float qscale) {
  __shared__ u16 As[2][128 * 64];
  __shared__ u16 Bs[2][128 * 64];
  const int z = blockIdx.z;
  const u16* A   = (z == 0) ? A0 : (z == 1) ? A1 : A2;
  const u16* Bw  = (z == 0) ? W0 : (z == 1) ? W1 : W2;
  const float* bias = (z == 0) ? b0 : (z == 1) ? b1 : b2;
  u16* outp = (z == 0) ? o0 : (z == 1) ? o1 : o2;
  const float scale = (z == 0) ? qscale : 1.0f;

  const int m0 = blockIdx.y * 128;
  const int n0 = blockIdx.x * 128;
  const int tid = threadIdx.x;
  const int w = tid >> 6, l = tid & 63;
  const int wr = w >> 1, wc = w & 1;
  const int lg = l >> 4, lr = l & 15;

  const int row0 = tid >> 3, slot0 = tid & 7;
  const int so = (slot0 ^ (row0 & 7)) << 3;
  const u16* Ag = A  + ((size_t)(m0 + row0)) * CDIM + so;
  const u16* Bg = Bw + ((size_t)(n0 + row0)) * CDIM + so;
  u16* Ad0 = As[0] + w * 512;  u16* Bd0 = Bs[0] + w * 512;
  u16* Ad1 = As[1] + w * 512;  u16* Bd1 = Bs[1] + w * 512;

  f32x4 acc[4][4] = {};

  GEMM_KLOOP(As, Bs, Ad0, Bd0, Ad1, Bd1)

#pragma unroll
  for (int fj = 0; fj < 4; ++fj) {
    int col = n0 + wc * 64 + fj * 16 + lr;
    float bv = bias[col];
    int h = col >> 6, d = col & 63;
#pragma unroll
    for (int fi = 0; fi < 4; ++fi) {
#pragma unroll
      for (int i = 0; i < 4; ++i) {
        int row = m0 + wr * 64 + fi * 16 + lg * 4 + i;
        float val = (acc[fi][fj][i] + bv) * scale;
        int b = row >> 11, t = row & 2047;
        if (z < 2)
          outp[(((size_t)(b * NHEAD + h)) * T_SEQ + t) * HDIM + d] = f2bf(val);
        else
          outp[(((size_t)(b * NHEAD + h)) * HDIM + d) * T_SEQ + t] = f2bf(val);
      }
    }
  }
}

// O-projection: C = A @ Wo^T + bo, fp32 out row-major.
__global__ __launch_bounds__(256)
void gemm_bt0(const u16* __restrict__ A, const u16* __restrict__ Bw,
              const float* __restrict__ bias, float* __restrict__ outp) {
  __shared__ u16 As[2][128 * 64];
  __shared__ u16 Bs[2][128 * 64];
  const int m0 = blockIdx.y * 128;
  const int n0 = blockIdx.x * 128;
  const int tid = threadIdx.x;
  const int w = tid >> 6, l = tid & 63;
  const int wr = w >> 1, wc = w & 1;
  const int lg = l >> 4, lr = l & 15;

  const int row0 = tid >> 3, slot0 = tid & 7;
  const int so = (slot0 ^ (row0 & 7)) << 3;
  const u16* Ag = A  + ((size_t)(m0 + row0)) * CDIM + so;
  const u16* Bg = Bw + ((size_t)(n0 + row0)) * CDIM + so;
  u16* Ad0 = As[0] + w * 512;  u16* Bd0 = Bs[0] + w * 512;
  u16* Ad1 = As[1] + w * 512;  u16* Bd1 = Bs[1] + w * 512;

  f32x4 acc[4][4] = {};

  GEMM_KLOOP(As, Bs, Ad0, Bd0, Ad1, Bd1)

#pragma unroll
  for (int fj = 0; fj < 4; ++fj) {
    int col = n0 + wc * 64 + fj * 16 + lr;
    float bv = bias[col];
#pragma unroll
    for (int fi = 0; fi < 4; ++fi) {
#pragma unroll
      for (int i = 0; i < 4; ++i) {
        int row = m0 + wr * 64 + fi * 16 + lg * 4 + i;
        outp[(size_t)row * CDIM + col] = acc[fi][fj][i] + bv;
      }
    }
  }
}

// ---------------- Flash attention (defer-max online softmax) ----------------
// Qh/Kh: [B*H][T][Dh] bf16 (Q pre-scaled by log2e/8 -> log2-domain logits).
// Vt: [B*H][Dh][T] bf16. Ao: [B][T][C] bf16.
// Swapped QK^T: wave computes S^T[kv][16 q-rows]; lane lr owns one q-row.
// Lane-local tile-max on the common path; cross-lane max + rescale only on
// the rare (__all-uniform) path. Row-sum kept as 4 lane-local partials.

__device__ __forceinline__ void attn_stage(const u16* Kg, const u16* Vg, u16* Kd, u16* Vd) {
#pragma unroll
  for (int c = 0; c < 2; ++c) {          // 4 vm-ops total
    gll16(Kg + c * 32 * HDIM,  Kd + c * 2048);
    gll16(Vg + c * 32 * T_SEQ, Vd + c * 2048);
  }
}

__device__ __forceinline__ void attn_process(const u16* Ks, const u16* Vs, u16* pw,
                                             bf16x8 qf0, bf16x8 qf1,
                                             f32x4 (&acc)[4], f32x4& lsum, float& m_run,
                                             int lg, int lr) {
  // S^T = K @ Q^T
  f32x4 s[4] = {};
  __builtin_amdgcn_s_setprio(1);
#pragma unroll
  for (int kk = 0; kk < 2; ++kk) {
    bf16x8 qf = kk ? qf1 : qf0;
#pragma unroll
    for (int fn = 0; fn < 4; ++fn) {
      int r = fn * 16 + lr;
      bf16x8 kf = *(const bf16x8*)((const char*)Ks + r * 128 + ((lg * 16 + kk * 64) ^ ((r & 7) << 4)));
      s[fn] = __builtin_amdgcn_mfma_f32_16x16x32_bf16(kf, qf, s[fn], 0, 0, 0);
    }
  }
  __builtin_amdgcn_s_setprio(0);

  // lane-local tile max; cross-lane reduce deferred into the rare path.
  // (any lane-local > thr) <=> (any row-max > thr): identical predicate.
  float t0 = fmaxf(fmaxf(s[0][0], s[0][1]), fmaxf(s[0][2], s[0][3]));
  float t1 = fmaxf(fmaxf(s[1][0], s[1][1]), fmaxf(s[1][2], s[1][3]));
  float t2 = fmaxf(fmaxf(s[2][0], s[2][1]), fmaxf(s[2][2], s[2][3]));
  float t3 = fmaxf(fmaxf(s[3][0], s[3][1]), fmaxf(s[3][2], s[3][3]));
  float tl = fmaxf(fmaxf(t0, t1), fmaxf(t2, t3));
  if (!__all(tl <= m_run + 8.f)) {
    float tmax = fmaxf(tl, __shfl_xor(tl, 16));
    tmax = fmaxf(tmax, __shfl_xor(tmax, 32));
    float m_new = fmaxf(m_run, tmax);
    float alpha = EXP2(m_run - m_new);
    lsum[0] *= alpha; lsum[1] *= alpha; lsum[2] *= alpha; lsum[3] *= alpha;
#pragma unroll
    for (int fd = 0; fd < 4; ++fd) {
      acc[fd][0] *= alpha; acc[fd][1] *= alpha;
      acc[fd][2] *= alpha; acc[fd][3] *= alpha;
    }
    m_run = m_new;
  }

  // p = 2^(s - m_run); accumulate lane-local row-sum partials; pack to LDS
#pragma unroll
  for (int fn = 0; fn < 4; ++fn) {
    float p0 = EXP2(s[fn][0] - m_run);
    float p1 = EXP2(s[fn][1] - m_run);
    float p2 = EXP2(s[fn][2] - m_run);
    float p3 = EXP2(s[fn][3] - m_run);
    lsum[fn] += (p0 + p1) + (p2 + p3);
    uint2 pk;
    pk.x = cvt_pk_bf16(p0, p1);
    pk.y = cvt_pk_bf16(p2, p3);
    *(uint2*)((char*)pw + lr * 128 + ((fn * 32 + lg * 8) ^ ((lr & 7) << 4))) = pk;
  }

  // O^T[d][m] += sum_n Vt[d][n] * P^T[n][m]   (Ps is per-wave: no barrier)
#pragma unroll
  for (int kk = 0; kk < 2; ++kk) {
    bf16x8 pf = *(const bf16x8*)((const char*)pw + lr * 128 + ((lg * 16 + kk * 64) ^ ((lr & 7) << 4)));
    __builtin_amdgcn_s_setprio(1);
#pragma unroll
    for (int fd = 0; fd < 4; ++fd) {
      int r = fd * 16 + lr;
      bf16x8 vf = *(const bf16x8*)((const char*)Vs + r * 128 + ((lg * 16 + kk * 64) ^ ((r & 7) << 4)));
      acc[fd] = __builtin_amdgcn_mfma_f32_16x16x32_bf16(vf, pf, acc[fd], 0, 0, 0);
    }
    __builtin_amdgcn_s_setprio(0);
  }
}

__global__ __launch_bounds__(256)
void attn_fused(const u16* __restrict__ Qh, const u16* __restrict__ Kh,
                const u16* __restrict__ Vt, u16* __restrict__ Ao) {
  __shared__ u16 Ks[2][64 * 64];
  __shared__ u16 Vs[2][64 * 64];
  __shared__ u16 Ps[4][16 * 64];
  const int bh = blockIdx.y;
  const int q0 = blockIdx.x * 64;
  const int tid = threadIdx.x;
  const int w = tid >> 6, l = tid & 63;
  const int lg = l >> 4, lr = l & 15;

  const u16* qptr = Qh + ((size_t)bh * T_SEQ + q0 + w * 16 + lr) * HDIM + lg * 8;
  bf16x8 qf0 = *(const bf16x8*)qptr;
  bf16x8 qf1 = *(const bf16x8*)(qptr + 32);

  const int row0 = tid >> 3, slot0 = tid & 7;
  const int so = (slot0 ^ (row0 & 7)) << 3;
  const u16* Kg = Kh + ((size_t)bh * T_SEQ + row0) * HDIM + so;
  const u16* Vg = Vt + ((size_t)bh * HDIM + row0) * T_SEQ + so;
  u16* Kd0 = Ks[0] + w * 512;  u16* Vd0 = Vs[0] + w * 512;
  u16* Kd1 = Ks[1] + w * 512;  u16* Vd1 = Vs[1] + w * 512;

  f32x4 acc[4] = {};
  f32x4 lsum = {};
  float m_run = -1e30f;
  u16* pw = Ps[w];

  // Counted-vmcnt double-buffered KV loop (see GEMM_KLOOP race analysis).
  attn_stage(Kg, Vg, Kd0, Vd0);
#pragma unroll 1
  for (int kv = 0; kv < 32; ++kv) {
    wg_barrier();                               // barA: buf[(kv+1)&1] free
    int nt = (kv + 1 < 32) ? kv + 1 : 31;
    if (kv & 1) attn_stage(Kg + (size_t)nt * 64 * HDIM, Vg + nt * 64, Kd0, Vd0);
    else        attn_stage(Kg + (size_t)nt * 64 * HDIM, Vg + nt * 64, Kd1, Vd1);
    WAIT_VM(4);                                 // my tile-kv loads landed
    wg_barrier();                               // barB: everyone's landed
    attn_process((kv & 1) ? Ks[1] : Ks[0], (kv & 1) ? Vs[1] : Vs[0],
                 pw, qf0, qf1, acc, lsum, m_run, lg, lr);
  }

  float lr_sum = (lsum[0] + lsum[1]) + (lsum[2] + lsum[3]);
  lr_sum += __shfl_xor(lr_sum, 16);
  lr_sum += __shfl_xor(lr_sum, 32);
  float inv = 1.f / lr_sum;

  int b = bh >> 4, h = bh & 15;
  u16* orow = Ao + ((size_t)(b * T_SEQ + q0 + w * 16 + lr)) * CDIM + h * HDIM;
#pragma unroll
  for (int fd = 0; fd < 4; ++fd) {
    uint2 ov;
    ov.x = cvt_pk_bf16(acc[fd][0] * inv, acc[fd][1] * inv);
    ov.y = cvt_pk_bf16(acc[fd][2] * inv, acc[fd][3] * inv);
    *(uint2*)(orow + fd * 16 + lg * 4) = ov;
  }
}

extern "C" void kernel_launch(void* const* d_in, const int* in_sizes, int n_in,
                              void* d_out, int out_size, void* d_ws, size_t ws_size,
                              hipStream_t stream) {
  const float* q  = (const float*)d_in[0];
  const float* k  = (const float*)d_in[1];
  const float* v  = (const float*)d_in[2];
  const float* Wq = (const float*)d_in[3];
  const float* bq = (const float*)d_in[4];
  const float* Wk = (const float*)d_in[5];
  const float* bk = (const float*)d_in[6];
  const float* Wv = (const float*)d_in[7];
  const float* bv = (const float*)d_in[8];
  const float* Wo = (const float*)d_in[9];
  const float* bo = (const float*)d_in[10];

  char* ws = (char*)d_ws;
  size_t off = 0;
  auto alloc = [&](size_t n) { void* p = ws + off; off += (n + 255) & ~(size_t)255; return p; };
  const size_t NX = (size_t)MROWS * CDIM;  // 4M elements
  const size_t NW = (size_t)CDIM * CDIM;   // 1M elements
  u16* qb  = (u16*)alloc(NX * 2);
  u16* kb  = (u16*)alloc(NX * 2);
  u16* vb  = (u16*)alloc(NX * 2);
  u16* Wqb = (u16*)alloc(NW * 2);
  u16* Wkb = (u16*)alloc(NW * 2);
  u16* Wvb = (u16*)alloc(NW * 2);
  u16* Wob = (u16*)alloc(NW * 2);
  u16* Qhp = (u16*)alloc(NX * 2);
  u16* Khp = (u16*)alloc(NX * 2);
  u16* Vtp = (u16*)alloc(NX * 2);
  u16* Aop = (u16*)alloc(NX * 2);

  cvt_all<<<2048, 256, 0, stream>>>(q, k, v, Wq, Wk, Wv, Wo,
                                    qb, kb, vb, Wqb, Wkb, Wvb, Wob);

  const float qscale = 0.18033688011112042f; // log2(e)/8 -> softmax in exp2 domain
  gemm_qkv<<<dim3(CDIM / 128, MROWS / 128, 3), 256, 0, stream>>>(
      qb, kb, vb, Wqb, Wkb, Wvb, bq, bk, bv, Qhp, Khp, Vtp, qscale);

  attn_fused<<<dim3(T_SEQ / 64, 32), 256, 0, stream>>>(Qhp, Khp, Vtp, Aop);

  gemm_bt0<<<dim3(CDIM / 128, MROWS / 128), 256, 0, stream>>>(Aop, Wob, bo, (float*)d_out);

  (void)in_sizes; (void)n_in; (void)out_size; (void)ws_size;
}

// Round 6
// 136.002 us; speedup vs baseline: 1.5098x; 1.0343x over previous
//
#include <hip/hip_runtime.h>
#include <stdint.h>

#define T_SEQ 2048
#define CDIM 1024
#define NHEAD 16
#define HDIM 64
#define MROWS 4096   // B*T

typedef unsigned short u16;
typedef __attribute__((ext_vector_type(8))) short bf16x8;
typedef __attribute__((ext_vector_type(4))) float f32x4;
typedef __attribute__((ext_vector_type(16))) float f32x16;
typedef __attribute__((ext_vector_type(4))) unsigned short u16x4;
typedef __attribute__((ext_vector_type(4))) unsigned int uint4v;

#if __has_builtin(__builtin_amdgcn_exp2f)
#define EXP2(x) __builtin_amdgcn_exp2f(x)
#else
#define EXP2(x) exp2f(x)
#endif

__device__ __forceinline__ u16 f2bf(float f) {
  unsigned u = __builtin_bit_cast(unsigned, f);
  u += 0x7fffu + ((u >> 16) & 1u);
  return (u16)(u >> 16);
}

__device__ __forceinline__ unsigned cvt_pk_bf16(float lo, float hi) {
  unsigned r;
  asm("v_cvt_pk_bf16_f32 %0, %1, %2" : "=v"(r) : "v"(lo), "v"(hi));
  return r;
}

// v_permlane32_swap_b32: a' = {a[0:31], b[0:31]}, b' = {a[32:63], b[32:63]}
__device__ __forceinline__ void pls(unsigned &a, unsigned &b) {
  asm("v_permlane32_swap_b32 %0, %1" : "+v"(a), "+v"(b));
}

__device__ __forceinline__ void gll16(const void* g, void* l) {
  __builtin_amdgcn_global_load_lds((__attribute__((address_space(1))) void*)(g),
                                   (__attribute__((address_space(3))) void*)(l),
                                   16, 0, 0);
}

// Raw workgroup barrier WITHOUT the vmcnt(0) drain __syncthreads() implies.
__device__ __forceinline__ void wg_barrier() {
  asm volatile("" ::: "memory");
  __builtin_amdgcn_s_barrier();
  asm volatile("" ::: "memory");
}

// Wait until <= N vector-memory ops outstanding.
#define WAIT_VM(N) do { __builtin_amdgcn_s_waitcnt(0xF00 | 0x70 | (N)); \
                        asm volatile("" ::: "memory"); } while (0)

// One fused conversion pass for all 7 fp32->bf16 inputs.
__global__ __launch_bounds__(256)
void cvt_all(const float* __restrict__ q, const float* __restrict__ k, const float* __restrict__ v,
             const float* __restrict__ wq, const float* __restrict__ wk,
             const float* __restrict__ wv, const float* __restrict__ wo,
             u16* __restrict__ qb, u16* __restrict__ kb, u16* __restrict__ vb,
             u16* __restrict__ wqb, u16* __restrict__ wkb, u16* __restrict__ wvb, u16* __restrict__ wob) {
  int b = blockIdx.x;
  const float* src; u16* dst; int base;
  if (b < 1536) {
    int s = b >> 9;
    src = (s == 0) ? q : (s == 1) ? k : v;
    dst = (s == 0) ? qb : (s == 1) ? kb : vb;
    base = (b & 511) * 2048;
  } else {
    int s = (b - 1536) >> 7;
    src = (s == 0) ? wq : (s == 1) ? wk : (s == 2) ? wv : wo;
    dst = (s == 0) ? wqb : (s == 1) ? wkb : (s == 2) ? wvb : wob;
    base = ((b - 1536) & 127) * 2048;
  }
#pragma unroll
  for (int j = 0; j < 8; ++j) {
    int i = base + j * 256 + threadIdx.x;
    float4 a = ((const float4*)src)[i];
    u16x4 o = { f2bf(a.x), f2bf(a.y), f2bf(a.z), f2bf(a.w) };
    ((u16x4*)dst)[i] = o;
  }
}

// ---------------- GEMM core pieces (unchanged from round 5) ----------------

__device__ __forceinline__ void gemm_stage(const u16* Ag, const u16* Bg, u16* Ad, u16* Bd) {
#pragma unroll
  for (int c = 0; c < 4; ++c) {          // 8 vm-ops total
    gll16(Ag + c * 32 * CDIM, Ad + c * 2048);
    gll16(Bg + c * 32 * CDIM, Bd + c * 2048);
  }
}

__device__ __forceinline__ void gemm_compute(const u16* As, const u16* Bs,
                                             f32x4 (&acc)[4][4],
                                             int wr, int wc, int lg, int lr) {
#pragma unroll
  for (int kk = 0; kk < 2; ++kk) {
    bf16x8 af[4], bfr[4];
#pragma unroll
    for (int f = 0; f < 4; ++f) {
      int ra = wr * 64 + f * 16 + lr;
      af[f]  = *(const bf16x8*)((const char*)As + ra * 128 + ((lg * 16 + kk * 64) ^ ((ra & 7) << 4)));
      int rb = wc * 64 + f * 16 + lr;
      bfr[f] = *(const bf16x8*)((const char*)Bs + rb * 128 + ((lg * 16 + kk * 64) ^ ((rb & 7) << 4)));
    }
#pragma unroll
    for (int i = 0; i < 4; ++i)
#pragma unroll
      for (int j = 0; j < 4; ++j)
        acc[i][j] = __builtin_amdgcn_mfma_f32_16x16x32_bf16(af[i], bfr[j], acc[i][j], 0, 0, 0);
  }
}

#define GEMM_KLOOP(As, Bs, Ad0, Bd0, Ad1, Bd1)                                 \
  gemm_stage(Ag, Bg, Ad0, Bd0);                                                \
  _Pragma("unroll 1")                                                          \
  for (int kt = 0; kt < 16; ++kt) {                                            \
    wg_barrier();                                                              \
    int nt = (kt + 1 < 16) ? kt + 1 : 15;                                      \
    if (kt & 1) gemm_stage(Ag + nt * 64, Bg + nt * 64, Ad0, Bd0);              \
    else        gemm_stage(Ag + nt * 64, Bg + nt * 64, Ad1, Bd1);              \
    WAIT_VM(8);                                                                \
    wg_barrier();                                                              \
    gemm_compute((kt & 1) ? As[1] : As[0], (kt & 1) ? Bs[1] : Bs[0],           \
                 acc, wr, wc, lg, lr);                                         \
  }

// Fused Q/K/V projection GEMMs: z = blockIdx.z selects the projection.
__global__ __launch_bounds__(256)
void gemm_qkv(const u16* __restrict__ A0, const u16* __restrict__ A1, const u16* __restrict__ A2,
              const u16* __restrict__ W0, const u16* __restrict__ W1, const u16* __restrict__ W2,
              const float* __restrict__ b0, const float* __restrict__ b1, const float* __restrict__ b2,
              u16* __restrict__ o0, u16* __restrict__ o1, u16* __restrict__ o2,
              float qscale) {
  __shared__ u16 As[2][128 * 64];
  __shared__ u16 Bs[2][128 * 64];
  const int z = blockIdx.z;
  const u16* A   = (z == 0) ? A0 : (z == 1) ? A1 : A2;
  const u16* Bw  = (z == 0) ? W0 : (z == 1) ? W1 : W2;
  const float* bias = (z == 0) ? b0 : (z == 1) ? b1 : b2;
  u16* outp = (z == 0) ? o0 : (z == 1) ? o1 : o2;
  const float scale = (z == 0) ? qscale : 1.0f;

  const int m0 = blockIdx.y * 128;
  const int n0 = blockIdx.x * 128;
  const int tid = threadIdx.x;
  const int w = tid >> 6, l = tid & 63;
  const int wr = w >> 1, wc = w & 1;
  const int lg = l >> 4, lr = l & 15;

  const int row0 = tid >> 3, slot0 = tid & 7;
  const int so = (slot0 ^ (row0 & 7)) << 3;
  const u16* Ag = A  + ((size_t)(m0 + row0)) * CDIM + so;
  const u16* Bg = Bw + ((size_t)(n0 + row0)) * CDIM + so;
  u16* Ad0 = As[0] + w * 512;  u16* Bd0 = Bs[0] + w * 512;
  u16* Ad1 = As[1] + w * 512;  u16* Bd1 = Bs[1] + w * 512;

  f32x4 acc[4][4] = {};

  GEMM_KLOOP(As, Bs, Ad0, Bd0, Ad1, Bd1)

#pragma unroll
  for (int fj = 0; fj < 4; ++fj) {
    int col = n0 + wc * 64 + fj * 16 + lr;
    float bv = bias[col];
    int h = col >> 6, d = col & 63;
#pragma unroll
    for (int fi = 0; fi < 4; ++fi) {
#pragma unroll
      for (int i = 0; i < 4; ++i) {
        int row = m0 + wr * 64 + fi * 16 + lg * 4 + i;
        float val = (acc[fi][fj][i] + bv) * scale;
        int b = row >> 11, t = row & 2047;
        if (z < 2)
          outp[(((size_t)(b * NHEAD + h)) * T_SEQ + t) * HDIM + d] = f2bf(val);
        else
          outp[(((size_t)(b * NHEAD + h)) * HDIM + d) * T_SEQ + t] = f2bf(val);
      }
    }
  }
}

// O-projection: C = A @ Wo^T + bo, fp32 out row-major.
__global__ __launch_bounds__(256)
void gemm_bt0(const u16* __restrict__ A, const u16* __restrict__ Bw,
              const float* __restrict__ bias, float* __restrict__ outp) {
  __shared__ u16 As[2][128 * 64];
  __shared__ u16 Bs[2][128 * 64];
  const int m0 = blockIdx.y * 128;
  const int n0 = blockIdx.x * 128;
  const int tid = threadIdx.x;
  const int w = tid >> 6, l = tid & 63;
  const int wr = w >> 1, wc = w & 1;
  const int lg = l >> 4, lr = l & 15;

  const int row0 = tid >> 3, slot0 = tid & 7;
  const int so = (slot0 ^ (row0 & 7)) << 3;
  const u16* Ag = A  + ((size_t)(m0 + row0)) * CDIM + so;
  const u16* Bg = Bw + ((size_t)(n0 + row0)) * CDIM + so;
  u16* Ad0 = As[0] + w * 512;  u16* Bd0 = Bs[0] + w * 512;
  u16* Ad1 = As[1] + w * 512;  u16* Bd1 = Bs[1] + w * 512;

  f32x4 acc[4][4] = {};

  GEMM_KLOOP(As, Bs, Ad0, Bd0, Ad1, Bd1)

#pragma unroll
  for (int fj = 0; fj < 4; ++fj) {
    int col = n0 + wc * 64 + fj * 16 + lr;
    float bv = bias[col];
#pragma unroll
    for (int fi = 0; fi < 4; ++fi) {
#pragma unroll
      for (int i = 0; i < 4; ++i) {
        int row = m0 + wr * 64 + fi * 16 + lg * 4 + i;
        outp[(size_t)row * CDIM + col] = acc[fi][fj][i] + bv;
      }
    }
  }
}

// ---------------- Flash attention: 32x32x16 MFMA, in-register P ------------
// Qh/Kh: [B*H][T][Dh] bf16 (Q pre-scaled by log2e/8). Vt: [B*H][Dh][T] bf16.
// Block = 4 waves x 32 q-rows = 128 q. Swapped S^T = K @ Q^T per 32-kv subtile:
// C layout col=lane&31 = q (lane-local q-row), row = kv' = (r&3)+8*(r>>2)+4*hi.
// Lanes l and l+32 hold complementary kv halves of the SAME q-row -> softmax is
// in-lane + one shfl_xor(32). P converted to PV B-operand layout entirely in
// registers via cvt_pk + 2x permlane32_swap per k-step (no P LDS round-trip).

__device__ __forceinline__ void attn_stage(const u16* Kg, const u16* Vg, u16* Kd, u16* Vd) {
#pragma unroll
  for (int c = 0; c < 2; ++c) {          // 4 vm-ops total
    gll16(Kg + c * 32 * HDIM,  Kd + c * 2048);
    gll16(Vg + c * 32 * T_SEQ, Vd + c * 2048);
  }
}

__device__ __forceinline__ void attn_tile(const char* Kb, const char* Vb,
                                          const bf16x8 (&qf)[4],
                                          f32x16 (&acc)[2], f32x4& lsum, float& m_run,
                                          int lo5, int hi, int swz) {
  // S^T = K @ Q^T : two 32x32 kv-subtiles, K-accumulate over d (4 steps of 16)
  f32x16 s[2] = {};
  const int colK = 16 * hi;
  __builtin_amdgcn_s_setprio(1);
#pragma unroll
  for (int st = 0; st < 4; ++st) {
    bf16x8 k0 = *(const bf16x8*)(Kb + lo5 * 128        + ((32 * st + colK) ^ swz));
    bf16x8 k1 = *(const bf16x8*)(Kb + (lo5 + 32) * 128 + ((32 * st + colK) ^ swz));
    s[0] = __builtin_amdgcn_mfma_f32_32x32x16_bf16(k0, qf[st], s[0], 0, 0, 0);
    s[1] = __builtin_amdgcn_mfma_f32_32x32x16_bf16(k1, qf[st], s[1], 0, 0, 0);
  }
  __builtin_amdgcn_s_setprio(0);

  // lane-local tile max over the 32 scores of this lane's q-row
  float t[8];
#pragma unroll
  for (int i = 0; i < 8; ++i)
    t[i] = fmaxf(fmaxf(s[0][2 * i], s[0][2 * i + 1]), fmaxf(s[1][2 * i], s[1][2 * i + 1]));
  float u0 = fmaxf(fmaxf(t[0], t[1]), fmaxf(t[2], t[3]));
  float u1 = fmaxf(fmaxf(t[4], t[5]), fmaxf(t[6], t[7]));
  float tl = fmaxf(u0, u1);
  if (!__all(tl <= m_run + 8.f)) {       // defer-max (rare path)
    float tmax = fmaxf(tl, __shfl_xor(tl, 32));
    float m_new = fmaxf(m_run, tmax);
    float alpha = EXP2(m_run - m_new);
    lsum[0] *= alpha; lsum[1] *= alpha; lsum[2] *= alpha; lsum[3] *= alpha;
#pragma unroll
    for (int i = 0; i < 16; ++i) { acc[0][i] *= alpha; acc[1][i] *= alpha; }
    m_run = m_new;
  }

  // p = 2^(s - m_run); pack pairs (consecutive kv') to bf16 words
  unsigned pg[2][8];
#pragma unroll
  for (int g = 0; g < 8; ++g) {
    float a0 = EXP2(s[0][2 * g] - m_run), b0 = EXP2(s[0][2 * g + 1] - m_run);
    float a1 = EXP2(s[1][2 * g] - m_run), b1 = EXP2(s[1][2 * g + 1] - m_run);
    lsum[g & 3] += (a0 + b0) + (a1 + b1);
    pg[0][g] = cvt_pk_bf16(a0, b0);
    pg[1][g] = cvt_pk_bf16(a1, b1);
  }

  // Re-shuffle lane<->lane+32 halves into PV B-operand layout:
  // B word w needs kv' = 8*hi + 2w; lane holds kv' groups {0..3,8..11}+4hi.
  bf16x8 pb[4];
#pragma unroll
  for (int sub = 0; sub < 2; ++sub)
#pragma unroll
    for (int ks = 0; ks < 2; ++ks) {
      unsigned w0 = pg[sub][4 * ks + 0], w1 = pg[sub][4 * ks + 1];
      unsigned w2 = pg[sub][4 * ks + 2], w3 = pg[sub][4 * ks + 3];
      pls(w0, w2); pls(w1, w3);
      uint4v tt = { w0, w1, w2, w3 };
      pb[2 * sub + ks] = __builtin_bit_cast(bf16x8, tt);
    }

  // O^T[d][q] += V^T[d][kv] * P^T[kv][q] : 2 d-subtiles x 4 kv k-steps
  __builtin_amdgcn_s_setprio(1);
#pragma unroll
  for (int ks = 0; ks < 4; ++ks) {
    bf16x8 v0 = *(const bf16x8*)(Vb + lo5 * 128        + ((32 * ks + colK) ^ swz));
    bf16x8 v1 = *(const bf16x8*)(Vb + (lo5 + 32) * 128 + ((32 * ks + colK) ^ swz));
    acc[0] = __builtin_amdgcn_mfma_f32_32x32x16_bf16(v0, pb[ks], acc[0], 0, 0, 0);
    acc[1] = __builtin_amdgcn_mfma_f32_32x32x16_bf16(v1, pb[ks], acc[1], 0, 0, 0);
  }
  __builtin_amdgcn_s_setprio(0);
}

__global__ __launch_bounds__(256)
void attn_fused(const u16* __restrict__ Qh, const u16* __restrict__ Kh,
                const u16* __restrict__ Vt, u16* __restrict__ Ao) {
  __shared__ u16 Ks[2][64 * 64];
  __shared__ u16 Vs[2][64 * 64];
  const int bh = blockIdx.y;
  const int q0 = blockIdx.x * 128;
  const int tid = threadIdx.x;
  const int w = tid >> 6, l = tid & 63;
  const int lo5 = l & 31, hi = l >> 5;
  const int swz = (l & 7) << 4;          // (row&7)<<4 with row = 32k + lo5

  // Q fragments (B-operand): q-row = q0 + w*32 + lo5, k = 8*hi + j, d = 16s+k
  const u16* qptr = Qh + ((size_t)bh * T_SEQ + q0 + w * 32 + lo5) * HDIM + hi * 8;
  bf16x8 qf[4];
#pragma unroll
  for (int s = 0; s < 4; ++s) qf[s] = *(const bf16x8*)(qptr + 16 * s);

  const int row0 = tid >> 3, slot0 = tid & 7;
  const int so = (slot0 ^ (row0 & 7)) << 3;
  const u16* Kg = Kh + ((size_t)bh * T_SEQ + row0) * HDIM + so;
  const u16* Vg = Vt + ((size_t)bh * HDIM + row0) * T_SEQ + so;
  u16* Kd0 = Ks[0] + w * 512;  u16* Vd0 = Vs[0] + w * 512;
  u16* Kd1 = Ks[1] + w * 512;  u16* Vd1 = Vs[1] + w * 512;

  f32x16 acc[2] = {};
  f32x4 lsum = {};
  float m_run = -1e30f;

  attn_stage(Kg, Vg, Kd0, Vd0);
#pragma unroll 1
  for (int kv = 0; kv < 32; ++kv) {
    wg_barrier();                               // barA: buf[(kv+1)&1] free
    int nt = (kv + 1 < 32) ? kv + 1 : 31;
    if (kv & 1) attn_stage(Kg + (size_t)nt * 64 * HDIM, Vg + nt * 64, Kd0, Vd0);
    else        attn_stage(Kg + (size_t)nt * 64 * HDIM, Vg + nt * 64, Kd1, Vd1);
    WAIT_VM(4);                                 // my tile-kv loads landed
    wg_barrier();                               // barB: everyone's landed
    attn_tile((const char*)(kv & 1 ? Ks[1] : Ks[0]),
              (const char*)(kv & 1 ? Vs[1] : Vs[0]),
              qf, acc, lsum, m_run, lo5, hi, swz);
  }

  float ls = (lsum[0] + lsum[1]) + (lsum[2] + lsum[3]);
  ls += __shfl_xor(ls, 32);                     // combine the two kv halves
  float inv = 1.f / ls;

  // Coalesce the scattered O^T regs through per-wave LDS scratch (reuse Ks).
  wg_barrier();                                 // all waves done reading K/V
  char* os = (char*)(Ks[0]) + w * 4096;         // 4KB/wave: [32 q][64 d] bf16
#pragma unroll
  for (int dsub = 0; dsub < 2; ++dsub)
#pragma unroll
    for (int gg = 0; gg < 4; ++gg) {
      unsigned wa = cvt_pk_bf16(acc[dsub][4 * gg + 0] * inv, acc[dsub][4 * gg + 1] * inv);
      unsigned wb = cvt_pk_bf16(acc[dsub][4 * gg + 2] * inv, acc[dsub][4 * gg + 3] * inv);
      uint2 wv = { wa, wb };
      int byte = lo5 * 128 + (((32 * dsub + 8 * gg + 4 * hi) * 2) ^ swz);
      *(uint2*)(os + byte) = wv;
    }
  int b = bh >> 4, h = bh & 15;
#pragma unroll
  for (int c = 0; c < 4; ++c) {
    int qq = 8 * c + (l >> 3);
    uint4v ov = *(const uint4v*)(os + qq * 128 + ((16 * (l & 7)) ^ ((qq & 7) << 4)));
    *(uint4v*)(Ao + ((size_t)(b * T_SEQ + q0 + w * 32 + qq)) * CDIM + h * HDIM + (l & 7) * 8) = ov;
  }
}

extern "C" void kernel_launch(void* const* d_in, const int* in_sizes, int n_in,
                              void* d_out, int out_size, void* d_ws, size_t ws_size,
                              hipStream_t stream) {
  const float* q  = (const float*)d_in[0];
  const float* k  = (const float*)d_in[1];
  const float* v  = (const float*)d_in[2];
  const float* Wq = (const float*)d_in[3];
  const float* bq = (const float*)d_in[4];
  const float* Wk = (const float*)d_in[5];
  const float* bk = (const float*)d_in[6];
  const float* Wv = (const float*)d_in[7];
  const float* bv = (const float*)d_in[8];
  const float* Wo = (const float*)d_in[9];
  const float* bo = (const float*)d_in[10];

  char* ws = (char*)d_ws;
  size_t off = 0;
  auto alloc = [&](size_t n) { void* p = ws + off; off += (n + 255) & ~(size_t)255; return p; };
  const size_t NX = (size_t)MROWS * CDIM;  // 4M elements
  const size_t NW = (size_t)CDIM * CDIM;   // 1M elements
  u16* qb  = (u16*)alloc(NX * 2);
  u16* kb  = (u16*)alloc(NX * 2);
  u16* vb  = (u16*)alloc(NX * 2);
  u16* Wqb = (u16*)alloc(NW * 2);
  u16* Wkb = (u16*)alloc(NW * 2);
  u16* Wvb = (u16*)alloc(NW * 2);
  u16* Wob = (u16*)alloc(NW * 2);
  u16* Qhp = (u16*)alloc(NX * 2);
  u16* Khp = (u16*)alloc(NX * 2);
  u16* Vtp = (u16*)alloc(NX * 2);
  u16* Aop = (u16*)alloc(NX * 2);

  cvt_all<<<2048, 256, 0, stream>>>(q, k, v, Wq, Wk, Wv, Wo,
                                    qb, kb, vb, Wqb, Wkb, Wvb, Wob);

  const float qscale = 0.18033688011112042f; // log2(e)/8 -> softmax in exp2 domain
  gemm_qkv<<<dim3(CDIM / 128, MROWS / 128, 3), 256, 0, stream>>>(
      qb, kb, vb, Wqb, Wkb, Wvb, bq, bk, bv, Qhp, Khp, Vtp, qscale);

  attn_fused<<<dim3(T_SEQ / 128, 32), 256, 0, stream>>>(Qhp, Khp, Vtp, Aop);

  gemm_bt0<<<dim3(CDIM / 128, MROWS / 128), 256, 0, stream>>>(Aop, Wob, bo, (float*)d_out);

  (void)in_sizes; (void)n_in; (void)out_size; (void)ws_size;
}

// Round 7
// 129.208 us; speedup vs baseline: 1.5892x; 1.0526x over previous
//
#include <hip/hip_runtime.h>
#include <stdint.h>

#define T_SEQ 2048
#define CDIM 1024
#define NHEAD 16
#define HDIM 64
#define MROWS 4096   // B*T

typedef unsigned short u16;
typedef __attribute__((ext_vector_type(8))) short bf16x8;
typedef __attribute__((ext_vector_type(4))) float f32x4;
typedef __attribute__((ext_vector_type(16))) float f32x16;
typedef __attribute__((ext_vector_type(4))) unsigned short u16x4;
typedef __attribute__((ext_vector_type(4))) unsigned int uint4v;

#if __has_builtin(__builtin_amdgcn_exp2f)
#define EXP2(x) __builtin_amdgcn_exp2f(x)
#else
#define EXP2(x) exp2f(x)
#endif

__device__ __forceinline__ u16 f2bf(float f) {
  unsigned u = __builtin_bit_cast(unsigned, f);
  u += 0x7fffu + ((u >> 16) & 1u);
  return (u16)(u >> 16);
}

__device__ __forceinline__ unsigned cvt_pk_bf16(float lo, float hi) {
  unsigned r;
  asm("v_cvt_pk_bf16_f32 %0, %1, %2" : "=v"(r) : "v"(lo), "v"(hi));
  return r;
}

// v_permlane32_swap_b32: a' = {a[0:31], b[0:31]}, b' = {a[32:63], b[32:63]}
__device__ __forceinline__ void pls(unsigned &a, unsigned &b) {
  asm("v_permlane32_swap_b32 %0, %1" : "+v"(a), "+v"(b));
}

__device__ __forceinline__ void gll16(const void* g, void* l) {
  __builtin_amdgcn_global_load_lds((__attribute__((address_space(1))) void*)(g),
                                   (__attribute__((address_space(3))) void*)(l),
                                   16, 0, 0);
}

// Raw workgroup barrier WITHOUT the vmcnt(0) drain __syncthreads() implies.
__device__ __forceinline__ void wg_barrier() {
  asm volatile("" ::: "memory");
  __builtin_amdgcn_s_barrier();
  asm volatile("" ::: "memory");
}

// Wait until <= N vector-memory ops outstanding.
#define WAIT_VM(N) do { __builtin_amdgcn_s_waitcnt(0xF00 | 0x70 | (N)); \
                        asm volatile("" ::: "memory"); } while (0)

// One fused conversion pass for all 7 fp32->bf16 inputs.
__global__ __launch_bounds__(256)
void cvt_all(const float* __restrict__ q, const float* __restrict__ k, const float* __restrict__ v,
             const float* __restrict__ wq, const float* __restrict__ wk,
             const float* __restrict__ wv, const float* __restrict__ wo,
             u16* __restrict__ qb, u16* __restrict__ kb, u16* __restrict__ vb,
             u16* __restrict__ wqb, u16* __restrict__ wkb, u16* __restrict__ wvb, u16* __restrict__ wob) {
  int b = blockIdx.x;
  const float* src; u16* dst; int base;
  if (b < 1536) {
    int s = b >> 9;
    src = (s == 0) ? q : (s == 1) ? k : v;
    dst = (s == 0) ? qb : (s == 1) ? kb : vb;
    base = (b & 511) * 2048;
  } else {
    int s = (b - 1536) >> 7;
    src = (s == 0) ? wq : (s == 1) ? wk : (s == 2) ? wv : wo;
    dst = (s == 0) ? wqb : (s == 1) ? wkb : (s == 2) ? wvb : wob;
    base = ((b - 1536) & 127) * 2048;
  }
#pragma unroll
  for (int j = 0; j < 8; ++j) {
    int i = base + j * 256 + threadIdx.x;
    float4 a = ((const float4*)src)[i];
    u16x4 o = { f2bf(a.x), f2bf(a.y), f2bf(a.z), f2bf(a.w) };
    ((u16x4*)dst)[i] = o;
  }
}

// ---------------- GEMM core pieces (unchanged) ----------------

__device__ __forceinline__ void gemm_stage(const u16* Ag, const u16* Bg, u16* Ad, u16* Bd) {
#pragma unroll
  for (int c = 0; c < 4; ++c) {          // 8 vm-ops total
    gll16(Ag + c * 32 * CDIM, Ad + c * 2048);
    gll16(Bg + c * 32 * CDIM, Bd + c * 2048);
  }
}

__device__ __forceinline__ void gemm_compute(const u16* As, const u16* Bs,
                                             f32x4 (&acc)[4][4],
                                             int wr, int wc, int lg, int lr) {
#pragma unroll
  for (int kk = 0; kk < 2; ++kk) {
    bf16x8 af[4], bfr[4];
#pragma unroll
    for (int f = 0; f < 4; ++f) {
      int ra = wr * 64 + f * 16 + lr;
      af[f]  = *(const bf16x8*)((const char*)As + ra * 128 + ((lg * 16 + kk * 64) ^ ((ra & 7) << 4)));
      int rb = wc * 64 + f * 16 + lr;
      bfr[f] = *(const bf16x8*)((const char*)Bs + rb * 128 + ((lg * 16 + kk * 64) ^ ((rb & 7) << 4)));
    }
#pragma unroll
    for (int i = 0; i < 4; ++i)
#pragma unroll
      for (int j = 0; j < 4; ++j)
        acc[i][j] = __builtin_amdgcn_mfma_f32_16x16x32_bf16(af[i], bfr[j], acc[i][j], 0, 0, 0);
  }
}

#define GEMM_KLOOP(As, Bs, Ad0, Bd0, Ad1, Bd1)                                 \
  gemm_stage(Ag, Bg, Ad0, Bd0);                                                \
  _Pragma("unroll 1")                                                          \
  for (int kt = 0; kt < 16; ++kt) {                                            \
    wg_barrier();                                                              \
    int nt = (kt + 1 < 16) ? kt + 1 : 15;                                      \
    if (kt & 1) gemm_stage(Ag + nt * 64, Bg + nt * 64, Ad0, Bd0);              \
    else        gemm_stage(Ag + nt * 64, Bg + nt * 64, Ad1, Bd1);              \
    WAIT_VM(8);                                                                \
    wg_barrier();                                                              \
    gemm_compute((kt & 1) ? As[1] : As[0], (kt & 1) ? Bs[1] : Bs[0],           \
                 acc, wr, wc, lg, lr);                                         \
  }

// Fused Q/K/V projection GEMMs: z = blockIdx.z selects the projection.
__global__ __launch_bounds__(256)
void gemm_qkv(const u16* __restrict__ A0, const u16* __restrict__ A1, const u16* __restrict__ A2,
              const u16* __restrict__ W0, const u16* __restrict__ W1, const u16* __restrict__ W2,
              const float* __restrict__ b0, const float* __restrict__ b1, const float* __restrict__ b2,
              u16* __restrict__ o0, u16* __restrict__ o1, u16* __restrict__ o2,
              float qscale) {
  __shared__ u16 As[2][128 * 64];
  __shared__ u16 Bs[2][128 * 64];
  const int z = blockIdx.z;
  const u16* A   = (z == 0) ? A0 : (z == 1) ? A1 : A2;
  const u16* Bw  = (z == 0) ? W0 : (z == 1) ? W1 : W2;
  const float* bias = (z == 0) ? b0 : (z == 1) ? b1 : b2;
  u16* outp = (z == 0) ? o0 : (z == 1) ? o1 : o2;
  const float scale = (z == 0) ? qscale : 1.0f;

  const int m0 = blockIdx.y * 128;
  const int n0 = blockIdx.x * 128;
  const int tid = threadIdx.x;
  const int w = tid >> 6, l = tid & 63;
  const int wr = w >> 1, wc = w & 1;
  const int lg = l >> 4, lr = l & 15;

  const int row0 = tid >> 3, slot0 = tid & 7;
  const int so = (slot0 ^ (row0 & 7)) << 3;
  const u16* Ag = A  + ((size_t)(m0 + row0)) * CDIM + so;
  const u16* Bg = Bw + ((size_t)(n0 + row0)) * CDIM + so;
  u16* Ad0 = As[0] + w * 512;  u16* Bd0 = Bs[0] + w * 512;
  u16* Ad1 = As[1] + w * 512;  u16* Bd1 = Bs[1] + w * 512;

  f32x4 acc[4][4] = {};

  GEMM_KLOOP(As, Bs, Ad0, Bd0, Ad1, Bd1)

#pragma unroll
  for (int fj = 0; fj < 4; ++fj) {
    int col = n0 + wc * 64 + fj * 16 + lr;
    float bv = bias[col];
    int h = col >> 6, d = col & 63;
#pragma unroll
    for (int fi = 0; fi < 4; ++fi) {
#pragma unroll
      for (int i = 0; i < 4; ++i) {
        int row = m0 + wr * 64 + fi * 16 + lg * 4 + i;
        float val = (acc[fi][fj][i] + bv) * scale;
        int b = row >> 11, t = row & 2047;
        if (z < 2)
          outp[(((size_t)(b * NHEAD + h)) * T_SEQ + t) * HDIM + d] = f2bf(val);
        else
          outp[(((size_t)(b * NHEAD + h)) * HDIM + d) * T_SEQ + t] = f2bf(val);
      }
    }
  }
}

// O-projection: C = A @ Wo^T + bo, fp32 out row-major.
__global__ __launch_bounds__(256)
void gemm_bt0(const u16* __restrict__ A, const u16* __restrict__ Bw,
              const float* __restrict__ bias, float* __restrict__ outp) {
  __shared__ u16 As[2][128 * 64];
  __shared__ u16 Bs[2][128 * 64];
  const int m0 = blockIdx.y * 128;
  const int n0 = blockIdx.x * 128;
  const int tid = threadIdx.x;
  const int w = tid >> 6, l = tid & 63;
  const int wr = w >> 1, wc = w & 1;
  const int lg = l >> 4, lr = l & 15;

  const int row0 = tid >> 3, slot0 = tid & 7;
  const int so = (slot0 ^ (row0 & 7)) << 3;
  const u16* Ag = A  + ((size_t)(m0 + row0)) * CDIM + so;
  const u16* Bg = Bw + ((size_t)(n0 + row0)) * CDIM + so;
  u16* Ad0 = As[0] + w * 512;  u16* Bd0 = Bs[0] + w * 512;
  u16* Ad1 = As[1] + w * 512;  u16* Bd1 = Bs[1] + w * 512;

  f32x4 acc[4][4] = {};

  GEMM_KLOOP(As, Bs, Ad0, Bd0, Ad1, Bd1)

#pragma unroll
  for (int fj = 0; fj < 4; ++fj) {
    int col = n0 + wc * 64 + fj * 16 + lr;
    float bv = bias[col];
#pragma unroll
    for (int fi = 0; fi < 4; ++fi) {
#pragma unroll
      for (int i = 0; i < 4; ++i) {
        int row = m0 + wr * 64 + fi * 16 + lg * 4 + i;
        outp[(size_t)row * CDIM + col] = acc[fi][fj][i] + bv;
      }
    }
  }
}

// ---------------- Flash attention: 32x32x16, in-reg P, in-block KV-split ----
// Qh/Kh: [B*H][T][Dh] bf16 (Q pre-scaled by log2e/8). Vt: [B*H][Dh][T] bf16.
// Block = 512 threads = 8 waves. Waves 0-3 (grp0): q subtiles 0-3 vs EVEN kv
// tiles; waves 4-7 (grp1): same q vs ODD kv tiles. Per-wave flash partials
// (m, lsum, acc) merged at the end (standard softmax combine) via LDS.
// attn_tile math identical to round 6 (proven).

__device__ __forceinline__ void attn_tile(const char* Kb, const char* Vb,
                                          const bf16x8 (&qf)[4],
                                          f32x16 (&acc)[2], f32x4& lsum, float& m_run,
                                          int lo5, int hi, int swz) {
  // S^T = K @ Q^T : two 32x32 kv-subtiles, K-accumulate over d (4 steps of 16)
  f32x16 s[2] = {};
  const int colK = 16 * hi;
  __builtin_amdgcn_s_setprio(1);
#pragma unroll
  for (int st = 0; st < 4; ++st) {
    bf16x8 k0 = *(const bf16x8*)(Kb + lo5 * 128        + ((32 * st + colK) ^ swz));
    bf16x8 k1 = *(const bf16x8*)(Kb + (lo5 + 32) * 128 + ((32 * st + colK) ^ swz));
    s[0] = __builtin_amdgcn_mfma_f32_32x32x16_bf16(k0, qf[st], s[0], 0, 0, 0);
    s[1] = __builtin_amdgcn_mfma_f32_32x32x16_bf16(k1, qf[st], s[1], 0, 0, 0);
  }
  __builtin_amdgcn_s_setprio(0);

  // lane-local tile max over the 32 scores of this lane's q-row
  float t[8];
#pragma unroll
  for (int i = 0; i < 8; ++i)
    t[i] = fmaxf(fmaxf(s[0][2 * i], s[0][2 * i + 1]), fmaxf(s[1][2 * i], s[1][2 * i + 1]));
  float u0 = fmaxf(fmaxf(t[0], t[1]), fmaxf(t[2], t[3]));
  float u1 = fmaxf(fmaxf(t[4], t[5]), fmaxf(t[6], t[7]));
  float tl = fmaxf(u0, u1);
  if (!__all(tl <= m_run + 8.f)) {       // defer-max (rare path)
    float tmax = fmaxf(tl, __shfl_xor(tl, 32));
    float m_new = fmaxf(m_run, tmax);
    float alpha = EXP2(m_run - m_new);
    lsum[0] *= alpha; lsum[1] *= alpha; lsum[2] *= alpha; lsum[3] *= alpha;
#pragma unroll
    for (int i = 0; i < 16; ++i) { acc[0][i] *= alpha; acc[1][i] *= alpha; }
    m_run = m_new;
  }

  // p = 2^(s - m_run); pack pairs (consecutive kv') to bf16 words
  unsigned pg[2][8];
#pragma unroll
  for (int g = 0; g < 8; ++g) {
    float a0 = EXP2(s[0][2 * g] - m_run), b0 = EXP2(s[0][2 * g + 1] - m_run);
    float a1 = EXP2(s[1][2 * g] - m_run), b1 = EXP2(s[1][2 * g + 1] - m_run);
    lsum[g & 3] += (a0 + b0) + (a1 + b1);
    pg[0][g] = cvt_pk_bf16(a0, b0);
    pg[1][g] = cvt_pk_bf16(a1, b1);
  }

  // Re-shuffle lane<->lane+32 halves into PV B-operand layout.
  bf16x8 pb[4];
#pragma unroll
  for (int sub = 0; sub < 2; ++sub)
#pragma unroll
    for (int ks = 0; ks < 2; ++ks) {
      unsigned w0 = pg[sub][4 * ks + 0], w1 = pg[sub][4 * ks + 1];
      unsigned w2 = pg[sub][4 * ks + 2], w3 = pg[sub][4 * ks + 3];
      pls(w0, w2); pls(w1, w3);
      uint4v tt = { w0, w1, w2, w3 };
      pb[2 * sub + ks] = __builtin_bit_cast(bf16x8, tt);
    }

  // O^T[d][q] += V^T[d][kv] * P^T[kv][q]
  __builtin_amdgcn_s_setprio(1);
#pragma unroll
  for (int ks = 0; ks < 4; ++ks) {
    bf16x8 v0 = *(const bf16x8*)(Vb + lo5 * 128        + ((32 * ks + colK) ^ swz));
    bf16x8 v1 = *(const bf16x8*)(Vb + (lo5 + 32) * 128 + ((32 * ks + colK) ^ swz));
    acc[0] = __builtin_amdgcn_mfma_f32_32x32x16_bf16(v0, pb[ks], acc[0], 0, 0, 0);
    acc[1] = __builtin_amdgcn_mfma_f32_32x32x16_bf16(v1, pb[ks], acc[1], 0, 0, 0);
  }
  __builtin_amdgcn_s_setprio(0);
}

__global__ __launch_bounds__(512, 4)
void attn_fused(const u16* __restrict__ Qh, const u16* __restrict__ Kh,
                const u16* __restrict__ Vt, u16* __restrict__ Ao) {
  __shared__ u16 Ks[2][2][64 * 64];   // [dbuf][tile-parity]
  __shared__ u16 Vs[2][2][64 * 64];
  const int bh = blockIdx.y;
  const int q0 = blockIdx.x * 128;
  const int tid = threadIdx.x;
  const int w = tid >> 6, l = tid & 63;
  const int grp = w >> 2, wq = w & 3;      // kv-parity group, q subtile
  const int lo5 = l & 31, hi = l >> 5;
  const int swz = (l & 7) << 4;

  // Q fragments: q-row = q0 + wq*32 + lo5, d = 16*st + 8*hi + j
  const u16* qptr = Qh + ((size_t)bh * T_SEQ + q0 + wq * 32 + lo5) * HDIM + hi * 8;
  bf16x8 qf[4];
#pragma unroll
  for (int s = 0; s < 4; ++s) qf[s] = *(const bf16x8*)(qptr + 16 * s);

  // staging role: waves 0-3 stage K, 4-7 stage V; par = tile parity,
  // sub = row half. Each wave: 4 gll16 (8 rows each) = 32 rows of one tile.
  const int par = w & 1, sub = (w >> 1) & 1;
  const int row8 = l >> 3, slot = l & 7;

  auto stage = [&](int step, int db) {
    int t = 2 * step + par;
    if (grp == 0) {
      u16* dst = Ks[db][par] + sub * 32 * 64;
      const u16* src = Kh + ((size_t)bh * T_SEQ + (size_t)t * 64 + sub * 32 + row8) * HDIM
                          + ((slot ^ row8) << 3);
#pragma unroll
      for (int j = 0; j < 4; ++j)
        gll16(src + j * 8 * HDIM, dst + j * 8 * 64);
    } else {
      u16* dst = Vs[db][par] + sub * 32 * 64;
      const u16* src = Vt + ((size_t)bh * HDIM + sub * 32 + row8) * T_SEQ + (size_t)t * 64
                          + ((slot ^ row8) << 3);
#pragma unroll
      for (int j = 0; j < 4; ++j)
        gll16(src + (size_t)j * 8 * T_SEQ, dst + j * 8 * 64);
    }
  };

  f32x16 acc[2] = {};
  f32x4 lsum = {};
  float m_run = -1e30f;

  stage(0, 0);
#pragma unroll 1
  for (int s = 0; s < 16; ++s) {
    wg_barrier();                               // barA: dbuf^1 free
    int ns = (s + 1 < 16) ? s + 1 : 15;
    stage(ns, (s + 1) & 1);
    WAIT_VM(4);                                 // my step-s loads landed
    wg_barrier();                               // barB: everyone's landed
    attn_tile((const char*)Ks[s & 1][grp], (const char*)Vs[s & 1][grp],
              qf, acc, lsum, m_run, lo5, hi, swz);
  }

  // -------- combine grp0/grp1 partials (flash merge) --------
  float ls = (lsum[0] + lsum[1]) + (lsum[2] + lsum[3]);
  ls += __shfl_xor(ls, 32);                     // both halves: full partial sum

  wg_barrier();                                 // staging buffers free
  float* ex = (float*)&Ks[0][0][0];             // [w][32]: m ; +256: l
  if (hi == 0) {
    ex[w * 32 + lo5] = m_run;
    ex[256 + w * 32 + lo5] = ls;
  }
  wg_barrier();
  const int ow = w ^ 4;                         // counterpart wave
  float m_oth = ex[ow * 32 + lo5];
  float l_oth = ex[256 + ow * 32 + lo5];
  float m_fin = fmaxf(m_run, m_oth);
  float fs = EXP2(m_run - m_fin);
  float fo = EXP2(m_oth - m_fin);
  float l_tot = ls * fs + l_oth * fo;
#pragma unroll
  for (int i = 0; i < 16; ++i) { acc[0][i] *= fs; acc[1][i] *= fs; }

  float* ab = (float*)&Vs[0][0][0];             // [wq][64 lanes][32] f32 = 32KB
  if (grp == 1) {
#pragma unroll
    for (int du = 0; du < 2; ++du)
#pragma unroll
      for (int c = 0; c < 4; ++c) {
        f32x4 t4 = { acc[du][4 * c + 0], acc[du][4 * c + 1],
                     acc[du][4 * c + 2], acc[du][4 * c + 3] };
        *(f32x4*)(ab + ((wq * 64 + l) * 32 + du * 16 + c * 4)) = t4;
      }
  }
  wg_barrier();
  if (grp == 0) {
#pragma unroll
    for (int du = 0; du < 2; ++du)
#pragma unroll
      for (int c = 0; c < 4; ++c) {
        f32x4 t4 = *(const f32x4*)(ab + ((wq * 64 + l) * 32 + du * 16 + c * 4));
        acc[du][4 * c + 0] += t4[0]; acc[du][4 * c + 1] += t4[1];
        acc[du][4 * c + 2] += t4[2]; acc[du][4 * c + 3] += t4[3];
      }
    float inv = 1.f / l_tot;
    // per-wave scratch (4KB) at Ks base + 4KB + wq*4KB (clear of ex region)
    char* os = (char*)&Ks[0][0][0] + 4096 + wq * 4096;
#pragma unroll
    for (int dsub = 0; dsub < 2; ++dsub)
#pragma unroll
      for (int gg = 0; gg < 4; ++gg) {
        unsigned wa = cvt_pk_bf16(acc[dsub][4 * gg + 0] * inv, acc[dsub][4 * gg + 1] * inv);
        unsigned wb = cvt_pk_bf16(acc[dsub][4 * gg + 2] * inv, acc[dsub][4 * gg + 3] * inv);
        uint2 wv = { wa, wb };
        int byte = lo5 * 128 + (((32 * dsub + 8 * gg + 4 * hi) * 2) ^ swz);
        *(uint2*)(os + byte) = wv;
      }
    int b = bh >> 4, h = bh & 15;
#pragma unroll
    for (int c = 0; c < 4; ++c) {
      int qq = 8 * c + (l >> 3);
      uint4v ov = *(const uint4v*)(os + qq * 128 + ((16 * (l & 7)) ^ ((qq & 7) << 4)));
      *(uint4v*)(Ao + ((size_t)(b * T_SEQ + q0 + wq * 32 + qq)) * CDIM + h * HDIM + (l & 7) * 8) = ov;
    }
  }
}

extern "C" void kernel_launch(void* const* d_in, const int* in_sizes, int n_in,
                              void* d_out, int out_size, void* d_ws, size_t ws_size,
                              hipStream_t stream) {
  const float* q  = (const float*)d_in[0];
  const float* k  = (const float*)d_in[1];
  const float* v  = (const float*)d_in[2];
  const float* Wq = (const float*)d_in[3];
  const float* bq = (const float*)d_in[4];
  const float* Wk = (const float*)d_in[5];
  const float* bk = (const float*)d_in[6];
  const float* Wv = (const float*)d_in[7];
  const float* bv = (const float*)d_in[8];
  const float* Wo = (const float*)d_in[9];
  const float* bo = (const float*)d_in[10];

  char* ws = (char*)d_ws;
  size_t off = 0;
  auto alloc = [&](size_t n) { void* p = ws + off; off += (n + 255) & ~(size_t)255; return p; };
  const size_t NX = (size_t)MROWS * CDIM;  // 4M elements
  const size_t NW = (size_t)CDIM * CDIM;   // 1M elements
  u16* qb  = (u16*)alloc(NX * 2);
  u16* kb  = (u16*)alloc(NX * 2);
  u16* vb  = (u16*)alloc(NX * 2);
  u16* Wqb = (u16*)alloc(NW * 2);
  u16* Wkb = (u16*)alloc(NW * 2);
  u16* Wvb = (u16*)alloc(NW * 2);
  u16* Wob = (u16*)alloc(NW * 2);
  u16* Qhp = (u16*)alloc(NX * 2);
  u16* Khp = (u16*)alloc(NX * 2);
  u16* Vtp = (u16*)alloc(NX * 2);
  u16* Aop = (u16*)alloc(NX * 2);

  cvt_all<<<2048, 256, 0, stream>>>(q, k, v, Wq, Wk, Wv, Wo,
                                    qb, kb, vb, Wqb, Wkb, Wvb, Wob);

  const float qscale = 0.18033688011112042f; // log2(e)/8 -> softmax in exp2 domain
  gemm_qkv<<<dim3(CDIM / 128, MROWS / 128, 3), 256, 0, stream>>>(
      qb, kb, vb, Wqb, Wkb, Wvb, bq, bk, bv, Qhp, Khp, Vtp, qscale);

  attn_fused<<<dim3(T_SEQ / 128, 32), 512, 0, stream>>>(Qhp, Khp, Vtp, Aop);

  gemm_bt0<<<dim3(CDIM / 128, MROWS / 128), 256, 0, stream>>>(Aop, Wob, bo, (float*)d_out);

  (void)in_sizes; (void)n_in; (void)out_size; (void)ws_size;
}